// Round 5
// baseline (463.046 us; speedup 1.0000x reference)
//
#include <hip/hip_runtime.h>

// relationalGraphStack — round 4
// Changes vs R3:
//  - k_count: int cnt atomic only (deg atomic removed). New k_norm normalizes
//    edge weights per segment after CSR build (no atomics, sequential).
//  - gather2 split into stats pass (no write) + normalize-write pass straight
//    to d_out; k_bnrelu4 on the 102MB output eliminated (~200MB HBM saved).
//  - s1/s2 stored bf16; atomic kernels at 2048 blocks.

#define GATHER_GRID 2048
#define SCAN_CHUNK 4096

typedef short bf16x8 __attribute__((ext_vector_type(8)));
typedef float f32x4 __attribute__((ext_vector_type(4)));

static __device__ __forceinline__ float bf2f(unsigned short u) {
  return __uint_as_float(((unsigned)u) << 16);
}
static __device__ __forceinline__ unsigned short f2bf(float f) {
  unsigned u = __float_as_uint(f);
  u += 0x7FFFu + ((u >> 16) & 1u);  // round to nearest even
  return (unsigned short)(u >> 16);
}

__global__ void k_zero(int* __restrict__ cnt, int n) {
  int i = blockIdx.x * blockDim.x + threadIdx.x;
  int stride = gridDim.x * blockDim.x;
  for (int k = i; k < n; k += stride) cnt[k] = 0;
}

__global__ void k_count(const int* __restrict__ node_out, const int* __restrict__ rel,
                        int* __restrict__ cnt, int E, int R) {
  int i = blockIdx.x * blockDim.x + threadIdx.x;
  int stride = gridDim.x * blockDim.x;
  for (int e = i; e < E; e += stride) {
    atomicAdd(&cnt[node_out[e] * R + rel[e]], 1);
  }
}

__global__ __launch_bounds__(256) void k_scan1(const int* __restrict__ cnt,
                                               int* __restrict__ bsum, int NR) {
  __shared__ int red[256];
  int tid = threadIdx.x;
  int base = blockIdx.x * SCAN_CHUNK;
  int s = 0;
  for (int i = tid; i < SCAN_CHUNK; i += 256) {
    int idx = base + i;
    if (idx < NR) s += cnt[idx];
  }
  red[tid] = s;
  __syncthreads();
  for (int off = 128; off > 0; off >>= 1) {
    if (tid < off) red[tid] += red[tid + off];
    __syncthreads();
  }
  if (tid == 0) bsum[blockIdx.x] = red[0];
}

__global__ void k_scan2(const int* __restrict__ bsum, int* __restrict__ bpre,
                        int* __restrict__ rowptr_end, int NB) {
  int lane = threadIdx.x;
  int carry = 0;
  for (int base = 0; base < NB; base += 64) {
    int i = base + lane;
    int v = (i < NB) ? bsum[i] : 0;
    int incl = v;
    #pragma unroll
    for (int off = 1; off < 64; off <<= 1) {
      int u = __shfl_up(incl, off);
      if (lane >= off) incl += u;
    }
    if (i < NB) bpre[i] = carry + incl - v;
    carry += __shfl(incl, 63);
  }
  if (lane == 0) *rowptr_end = carry;
}

__global__ __launch_bounds__(256) void k_scan3(const int* __restrict__ cnt,
                                               const int* __restrict__ bpre,
                                               int* __restrict__ rowptr,
                                               int* __restrict__ wptr, int NR) {
  __shared__ int wtot[4];
  int tid = threadIdx.x, lane = tid & 63, wid = tid >> 6;
  int base = blockIdx.x * SCAN_CHUNK + tid * 16;
  int v[16];
  int t = 0;
  #pragma unroll
  for (int i = 0; i < 16; i++) {
    int idx = base + i;
    v[i] = (idx < NR) ? cnt[idx] : 0;
    t += v[i];
  }
  int incl = t;
  #pragma unroll
  for (int off = 1; off < 64; off <<= 1) {
    int u = __shfl_up(incl, off);
    if (lane >= off) incl += u;
  }
  if (lane == 63) wtot[wid] = incl;
  __syncthreads();
  int woff = 0;
  for (int w = 0; w < wid; w++) woff += wtot[w];
  int start = bpre[blockIdx.x] + woff + incl - t;
  #pragma unroll
  for (int i = 0; i < 16; i++) {
    int idx = base + i;
    if (idx < NR) { rowptr[idx] = start; wptr[idx] = start; }
    start += v[i];
  }
}

// payload: ep[pos] = (src | rel<<16, RAW w as float bits)   [requires N <= 65536]
__global__ void k_fill(const float* __restrict__ w, const int* __restrict__ node_out,
                       const int* __restrict__ node_in, const int* __restrict__ rel,
                       int* __restrict__ wptr, int2* __restrict__ ep, int E, int R) {
  int i = blockIdx.x * blockDim.x + threadIdx.x;
  int stride = gridDim.x * blockDim.x;
  for (int e = i; e < E; e += stride) {
    int rr = rel[e];
    int seg = node_out[e] * R + rr;
    int pos = atomicAdd(&wptr[seg], 1);
    ep[pos] = make_int2(node_in[e] | (rr << 16), __float_as_int(w[e]));
  }
}

// per-segment weight normalization in-place (no atomics): ep.w /= sum(seg w)
__global__ void k_norm(const int* __restrict__ rowptr, int2* __restrict__ ep, int NR) {
  int s = blockIdx.x * blockDim.x + threadIdx.x;
  if (s >= NR) return;
  int k0 = rowptr[s], k1 = rowptr[s + 1];
  if (k0 >= k1) return;
  float d = 0.f;
  for (int k = k0; k < k1; k++) d += __int_as_float(ep[k].y);
  float inv = 1.f / d;
  for (int k = k0; k < k1; k++) {
    int2 v = ep[k];
    v.y = __float_as_int(__int_as_float(v.y) * inv);
    ep[k] = v;
  }
}

// f32 -> bf16 convert (x)
__global__ void k_f2b(const float4* __restrict__ in, ushort4* __restrict__ out, int n4) {
  int i = blockIdx.x * blockDim.x + threadIdx.x;
  int stride = gridDim.x * blockDim.x;
  for (int k = i; k < n4; k += stride) {
    float4 v = in[k];
    ushort4 o;
    o.x = f2bf(v.x); o.y = f2bf(v.y); o.z = f2bf(v.z); o.w = f2bf(v.w);
    out[k] = o;
  }
}

__global__ void k_packW(const float* __restrict__ Wlin1, const float* __restrict__ Wself1,
                        const float* __restrict__ Wlin2, const float* __restrict__ Wself2,
                        unsigned short* __restrict__ wb1, unsigned short* __restrict__ wb2,
                        int R) {
  int i = blockIdx.x * blockDim.x + threadIdx.x;
  int stride = gridDim.x * blockDim.x;
  int n1 = (R + 1) * 64 * 64;
  int n2 = 2 * 64 * 64;
  for (int k = i; k < n1 + n2; k += stride) {
    if (k < n1) {
      int r = k >> 6, d = k & 63;
      float v;
      if (r < R * 64) {
        int s = r >> 6, j = r & 63;
        v = Wlin1[j * (R * 64) + s * 64 + d];
      } else {
        v = Wself1[(r - R * 64) * 64 + d];
      }
      wb1[k] = f2bf(v);
    } else {
      int k2 = k - n1;
      int r = k2 >> 6, d = k2 & 63;
      float v = (r < 64) ? Wlin2[r * 64 + d] : Wself2[(r - 64) * 64 + d];
      wb2[k2] = f2bf(v);
    }
  }
}

// MFMA GEMM: slabs [0,nslab) -> bf16 outLinB; slab==nslab -> bf16 outSelf.
__global__ __launch_bounds__(256) void k_gemm_mfma(
    const unsigned short* __restrict__ A, int M,
    const unsigned short* __restrict__ Wb, int nslab,
    unsigned short* __restrict__ outLinB, unsigned short* __restrict__ outSelf) {
  int m0 = blockIdx.x * 64;
  int wid = threadIdx.x >> 6;
  int lane = threadIdx.x & 63;
  int mrow = m0 + wid * 16 + (lane & 15);
  int mload = (mrow < M) ? mrow : (M - 1);
  const unsigned short* arow = A + (size_t)mload * 64 + 8 * (lane >> 4);
  bf16x8 a0 = *(const bf16x8*)(arow);
  bf16x8 a1 = *(const bf16x8*)(arow + 32);
  int rbase = m0 + wid * 16 + ((lane >> 4) << 2);
  int cbase = lane & 15;
  for (int slab = 0; slab <= nslab; ++slab) {
    const unsigned short* wrow = Wb + ((size_t)slab * 64 + (lane & 15)) * 64 + 8 * (lane >> 4);
    unsigned short* op = (slab < nslab) ? (outLinB + (size_t)slab * M * 64) : outSelf;
    #pragma unroll
    for (int nt = 0; nt < 4; ++nt) {
      bf16x8 b0 = *(const bf16x8*)(wrow + nt * 16 * 64);
      bf16x8 b1 = *(const bf16x8*)(wrow + nt * 16 * 64 + 32);
      f32x4 c = {};
      c = __builtin_amdgcn_mfma_f32_16x16x32_bf16(a0, b0, c, 0, 0, 0);
      c = __builtin_amdgcn_mfma_f32_16x16x32_bf16(a1, b1, c, 0, 0, 0);
      int col = nt * 16 + cbase;
      #pragma unroll
      for (int rg = 0; rg < 4; ++rg) {
        int grow = rbase + rg;
        if (grow < M) op[(size_t)grow * 64 + col] = f2bf(c[rg]);
      }
    }
  }
}

// layer1 gather: flat edge range per node; h_pre[n,c] = s1[n,c] + sum w*y1[rel*N+src, c]
__global__ __launch_bounds__(256) void k_gather1(
    const int* __restrict__ rowptr, const int2* __restrict__ ep,
    const unsigned short* __restrict__ y1, const unsigned short* __restrict__ s1,
    unsigned short* __restrict__ h_pre, float* __restrict__ part, int N, int R) {
  int lane = threadIdx.x & 63;
  int wid = threadIdx.x >> 6;
  int l16 = lane & 15;
  int lg = lane >> 4;
  int c0 = l16 * 4;
  int gw = blockIdx.x * 4 + wid;
  int nw = gridDim.x * 4;
  float lsum[4] = {0.f, 0.f, 0.f, 0.f}, lsq[4] = {0.f, 0.f, 0.f, 0.f};
  for (int n = gw; n < N; n += nw) {
    int k0 = rowptr[n * R];
    int kend = rowptr[n * R + R];
    float a0 = 0.f, a1 = 0.f, a2 = 0.f, a3 = 0.f;
    #pragma unroll 2
    for (int k = k0 + lg; k < kend; k += 4) {
      int2 p = ep[k];
      int src = p.x & 0xFFFF;
      int rr = p.x >> 16;
      float w = __int_as_float(p.y);
      ushort4 u = *(const ushort4*)&y1[((size_t)(rr * N + src)) * 64 + c0];
      a0 = fmaf(w, bf2f(u.x), a0);
      a1 = fmaf(w, bf2f(u.y), a1);
      a2 = fmaf(w, bf2f(u.z), a2);
      a3 = fmaf(w, bf2f(u.w), a3);
    }
    a0 += __shfl_xor(a0, 16); a0 += __shfl_xor(a0, 32);
    a1 += __shfl_xor(a1, 16); a1 += __shfl_xor(a1, 32);
    a2 += __shfl_xor(a2, 16); a2 += __shfl_xor(a2, 32);
    a3 += __shfl_xor(a3, 16); a3 += __shfl_xor(a3, 32);
    if (lg == 0) {
      ushort4 su = *(const ushort4*)&s1[(size_t)n * 64 + c0];
      float v0 = a0 + bf2f(su.x), v1 = a1 + bf2f(su.y);
      float v2 = a2 + bf2f(su.z), v3 = a3 + bf2f(su.w);
      ushort4 o; o.x = f2bf(v0); o.y = f2bf(v1); o.z = f2bf(v2); o.w = f2bf(v3);
      *(ushort4*)&h_pre[(size_t)n * 64 + c0] = o;
      lsum[0] += v0; lsq[0] += v0 * v0;
      lsum[1] += v1; lsq[1] += v1 * v1;
      lsum[2] += v2; lsq[2] += v2 * v2;
      lsum[3] += v3; lsq[3] += v3 * v3;
    }
  }
  __shared__ float sp[4][16][4], sq[4][16][4];
  if (lg == 0) {
    #pragma unroll
    for (int i = 0; i < 4; i++) { sp[wid][l16][i] = lsum[i]; sq[wid][l16][i] = lsq[i]; }
  }
  __syncthreads();
  if (threadIdx.x < 64) {
    int j = threadIdx.x;
    float s = 0.f, q = 0.f;
    for (int w2 = 0; w2 < 4; w2++) { s += sp[w2][j >> 2][j & 3]; q += sq[w2][j >> 2][j & 3]; }
    part[(size_t)blockIdx.x * 128 + j] = s;
    part[(size_t)blockIdx.x * 128 + 64 + j] = q;
  }
}

// layer2 pass A: stats only, no output write.
__global__ __launch_bounds__(256) void k_gather2_stats(
    const int* __restrict__ rowptr, const int2* __restrict__ ep,
    const unsigned short* __restrict__ z, const unsigned short* __restrict__ s2,
    float* __restrict__ part, int N, int R) {
  int lane = threadIdx.x & 63;
  int wid = threadIdx.x >> 6;
  int l16 = lane & 15;
  int lg = lane >> 4;
  int c0 = l16 * 4;
  int gw = blockIdx.x * 4 + wid;
  int nw = gridDim.x * 4;
  float lsum[4] = {0.f, 0.f, 0.f, 0.f}, lsq[4] = {0.f, 0.f, 0.f, 0.f};
  for (int n = gw; n < N; n += nw) {
    ushort4 su = *(const ushort4*)&s2[(size_t)n * 64 + c0];
    float sv0 = bf2f(su.x), sv1 = bf2f(su.y), sv2 = bf2f(su.z), sv3 = bf2f(su.w);
    int segbase = n * R;
    int k1 = rowptr[segbase];
    for (int r = 0; r < R; r++) {
      int k0 = k1;
      k1 = rowptr[segbase + r + 1];
      float a0 = 0.f, a1 = 0.f, a2 = 0.f, a3 = 0.f;
      #pragma unroll 2
      for (int k = k0 + lg; k < k1; k += 4) {
        int2 p = ep[k];
        int src = p.x & 0xFFFF;
        float w = __int_as_float(p.y);
        ushort4 u = *(const ushort4*)&z[(size_t)src * 64 + c0];
        a0 = fmaf(w, bf2f(u.x), a0);
        a1 = fmaf(w, bf2f(u.y), a1);
        a2 = fmaf(w, bf2f(u.z), a2);
        a3 = fmaf(w, bf2f(u.w), a3);
      }
      a0 += __shfl_xor(a0, 16); a0 += __shfl_xor(a0, 32);
      a1 += __shfl_xor(a1, 16); a1 += __shfl_xor(a1, 32);
      a2 += __shfl_xor(a2, 16); a2 += __shfl_xor(a2, 32);
      a3 += __shfl_xor(a3, 16); a3 += __shfl_xor(a3, 32);
      if (lg == 0) {
        float v0 = a0 + sv0, v1 = a1 + sv1, v2 = a2 + sv2, v3 = a3 + sv3;
        lsum[0] += v0; lsq[0] += v0 * v0;
        lsum[1] += v1; lsq[1] += v1 * v1;
        lsum[2] += v2; lsq[2] += v2 * v2;
        lsum[3] += v3; lsq[3] += v3 * v3;
      }
    }
  }
  __shared__ float sp[4][16][4], sq[4][16][4];
  if (lg == 0) {
    #pragma unroll
    for (int i = 0; i < 4; i++) { sp[wid][l16][i] = lsum[i]; sq[wid][l16][i] = lsq[i]; }
  }
  __syncthreads();
  if (threadIdx.x < 64) {
    int j = threadIdx.x;
    float s = 0.f, q = 0.f;
    for (int w2 = 0; w2 < 4; w2++) { s += sp[w2][j >> 2][j & 3]; q += sq[w2][j >> 2][j & 3]; }
    part[(size_t)blockIdx.x * 128 + j] = s;
    part[(size_t)blockIdx.x * 128 + 64 + j] = q;
  }
}

// layer2 pass B: recompute and write NORMALIZED output (BN+relu applied).
__global__ __launch_bounds__(256) void k_gather2_write(
    const int* __restrict__ rowptr, const int2* __restrict__ ep,
    const unsigned short* __restrict__ z, const unsigned short* __restrict__ s2,
    const float* __restrict__ ss, float* __restrict__ out, int N, int R) {
  int lane = threadIdx.x & 63;
  int wid = threadIdx.x >> 6;
  int l16 = lane & 15;
  int lg = lane >> 4;
  int c0 = l16 * 4;
  float sc0 = ss[c0], sc1 = ss[c0 + 1], sc2 = ss[c0 + 2], sc3 = ss[c0 + 3];
  float sh0 = ss[64 + c0], sh1 = ss[64 + c0 + 1], sh2 = ss[64 + c0 + 2], sh3 = ss[64 + c0 + 3];
  int gw = blockIdx.x * 4 + wid;
  int nw = gridDim.x * 4;
  for (int n = gw; n < N; n += nw) {
    ushort4 su = *(const ushort4*)&s2[(size_t)n * 64 + c0];
    float sv0 = bf2f(su.x), sv1 = bf2f(su.y), sv2 = bf2f(su.z), sv3 = bf2f(su.w);
    int segbase = n * R;
    int k1 = rowptr[segbase];
    for (int r = 0; r < R; r++) {
      int k0 = k1;
      k1 = rowptr[segbase + r + 1];
      float a0 = 0.f, a1 = 0.f, a2 = 0.f, a3 = 0.f;
      #pragma unroll 2
      for (int k = k0 + lg; k < k1; k += 4) {
        int2 p = ep[k];
        int src = p.x & 0xFFFF;
        float w = __int_as_float(p.y);
        ushort4 u = *(const ushort4*)&z[(size_t)src * 64 + c0];
        a0 = fmaf(w, bf2f(u.x), a0);
        a1 = fmaf(w, bf2f(u.y), a1);
        a2 = fmaf(w, bf2f(u.z), a2);
        a3 = fmaf(w, bf2f(u.w), a3);
      }
      a0 += __shfl_xor(a0, 16); a0 += __shfl_xor(a0, 32);
      a1 += __shfl_xor(a1, 16); a1 += __shfl_xor(a1, 32);
      a2 += __shfl_xor(a2, 16); a2 += __shfl_xor(a2, 32);
      a3 += __shfl_xor(a3, 16); a3 += __shfl_xor(a3, 32);
      if (lg == 0) {
        float v0 = fmaxf(fmaf(a0 + sv0, sc0, sh0), 0.f);
        float v1 = fmaxf(fmaf(a1 + sv1, sc1, sh1), 0.f);
        float v2 = fmaxf(fmaf(a2 + sv2, sc2, sh2), 0.f);
        float v3 = fmaxf(fmaf(a3 + sv3, sc3, sh3), 0.f);
        *(float4*)&out[((size_t)r * N + n) * 64 + c0] = make_float4(v0, v1, v2, v3);
      }
    }
  }
}

__global__ __launch_bounds__(1024) void k_bnstats(
    const float* __restrict__ part, int P, float M,
    const float* __restrict__ gamma, const float* __restrict__ beta,
    float* __restrict__ ss) {
  __shared__ float red[1024];
  int tid = threadIdx.x;
  int j = tid & 127;
  int g = tid >> 7;
  float acc = 0.f;
  for (int i = g; i < P; i += 8) acc += part[(size_t)i * 128 + j];
  red[tid] = acc;
  __syncthreads();
  if (tid < 128) {
    float s = 0.f;
    for (int gg = 0; gg < 8; gg++) s += red[gg * 128 + tid];
    red[tid] = s;
  }
  __syncthreads();
  if (tid < 64) {
    float s = red[tid], q = red[64 + tid];
    float mean = s / M;
    float var = q / M - mean * mean;
    float sc = gamma[tid] / sqrtf(var + 1e-5f);
    ss[tid] = sc;
    ss[64 + tid] = beta[tid] - mean * sc;
  }
}

// bn+relu, bf16 in -> bf16 out (h_pre -> h)
__global__ void k_bnrelu_b2b(const ushort4* __restrict__ in, ushort4* __restrict__ out,
                             const float* __restrict__ ss, long total4) {
  __shared__ float s_ss[128];
  if (threadIdx.x < 128) s_ss[threadIdx.x] = ss[threadIdx.x];
  __syncthreads();
  long i = (long)blockIdx.x * blockDim.x + threadIdx.x;
  long stride = (long)gridDim.x * blockDim.x;
  for (long k = i; k < total4; k += stride) {
    ushort4 v = in[k];
    int j0 = ((int)k & 15) * 4;
    ushort4 o;
    o.x = f2bf(fmaxf(fmaf(bf2f(v.x), s_ss[j0 + 0], s_ss[64 + j0 + 0]), 0.f));
    o.y = f2bf(fmaxf(fmaf(bf2f(v.y), s_ss[j0 + 1], s_ss[64 + j0 + 1]), 0.f));
    o.z = f2bf(fmaxf(fmaf(bf2f(v.z), s_ss[j0 + 2], s_ss[64 + j0 + 2]), 0.f));
    o.w = f2bf(fmaxf(fmaf(bf2f(v.w), s_ss[j0 + 3], s_ss[64 + j0 + 3]), 0.f));
    out[k] = o;
  }
}

extern "C" void kernel_launch(void* const* d_in, const int* in_sizes, int n_in,
                              void* d_out, int out_size, void* d_ws, size_t ws_size,
                              hipStream_t stream) {
  const float* x        = (const float*)d_in[0];
  const float* edge_w   = (const float*)d_in[1];
  const float* W_lin1   = (const float*)d_in[2];
  const float* W_self1  = (const float*)d_in[4];
  const float* gamma1   = (const float*)d_in[6];
  const float* beta1    = (const float*)d_in[7];
  const float* W_lin2   = (const float*)d_in[8];
  const float* W_self2  = (const float*)d_in[10];
  const float* gamma2   = (const float*)d_in[12];
  const float* beta2    = (const float*)d_in[13];
  const int* node_in    = (const int*)d_in[14];
  const int* node_out   = (const int*)d_in[15];
  const int* relation   = (const int*)d_in[16];

  int N = in_sizes[0] / 64;           // 50000
  int E = in_sizes[1];                // 800000
  int R = in_sizes[2] / (64 * 64);    // 8
  int NR = N * R;
  int NB = (NR + SCAN_CHUNK - 1) / SCAN_CHUNK;

  char* p = (char*)d_ws;
  auto alloc = [&](size_t bytes) { char* r = p; p += (bytes + 255) & ~(size_t)255; return r; };
  int* cnt      = (int*)alloc(4ull * NR);
  int* rowptr   = (int*)alloc(4ull * (NR + 1));
  int* wptr     = (int*)alloc(4ull * NR);
  int* bsum     = (int*)alloc(4ull * NB);
  int* bpre     = (int*)alloc(4ull * NB);
  int2* ep      = (int2*)alloc(8ull * E);
  unsigned short* wb1 = (unsigned short*)alloc(2ull * (R + 1) * 64 * 64);
  unsigned short* wb2 = (unsigned short*)alloc(2ull * 2 * 64 * 64);
  unsigned short* s1    = (unsigned short*)alloc(2ull * N * 64);
  unsigned short* h_pre = (unsigned short*)alloc(2ull * N * 64);
  unsigned short* z     = (unsigned short*)alloc(2ull * N * 64);
  unsigned short* s2    = (unsigned short*)alloc(2ull * N * 64);
  float* part   = (float*)alloc(4ull * GATHER_GRID * 128);
  float* ss1    = (float*)alloc(4ull * 128);
  float* ss2    = (float*)alloc(4ull * 128);

  // d_out scratch: y1 bf16 [0, 51.2MB), xb, hb after (all dead before pass B writes).
  unsigned short* y1 = (unsigned short*)d_out;
  unsigned short* xb = (unsigned short*)((char*)d_out + 2ull * R * N * 64);
  unsigned short* hb = xb + (size_t)N * 64;

  k_zero<<<512, 256, 0, stream>>>(cnt, NR);
  k_count<<<2048, 256, 0, stream>>>(node_out, relation, cnt, E, R);
  k_scan1<<<NB, 256, 0, stream>>>(cnt, bsum, NR);
  k_scan2<<<1, 64, 0, stream>>>(bsum, bpre, &rowptr[NR], NB);
  k_scan3<<<NB, 256, 0, stream>>>(cnt, bpre, rowptr, wptr, NR);
  k_fill<<<2048, 256, 0, stream>>>(edge_w, node_out, node_in, relation, wptr, ep, E, R);
  k_norm<<<(NR + 255) / 256, 256, 0, stream>>>(rowptr, ep, NR);

  k_f2b<<<1024, 256, 0, stream>>>((const float4*)x, (ushort4*)xb, N * 64 / 4);
  k_packW<<<64, 256, 0, stream>>>(W_lin1, W_self1, W_lin2, W_self2, wb1, wb2, R);

  // layer 1
  int mblocks = (N + 63) / 64;
  k_gemm_mfma<<<mblocks, 256, 0, stream>>>(xb, N, wb1, R, y1, s1);
  k_gather1<<<GATHER_GRID, 256, 0, stream>>>(rowptr, ep, y1, s1, h_pre, part, N, R);
  k_bnstats<<<1, 1024, 0, stream>>>(part, GATHER_GRID, (float)N, gamma1, beta1, ss1);
  k_bnrelu_b2b<<<2048, 256, 0, stream>>>((const ushort4*)h_pre, (ushort4*)hb, ss1, (long)N * 64 / 4);

  // layer 2: stats pass -> bnstats -> normalize-write pass
  k_gemm_mfma<<<mblocks, 256, 0, stream>>>(hb, N, wb2, 1, z, s2);
  k_gather2_stats<<<GATHER_GRID, 256, 0, stream>>>(rowptr, ep, z, s2, part, N, R);
  k_bnstats<<<1, 1024, 0, stream>>>(part, GATHER_GRID, (float)N * R, gamma2, beta2, ss2);
  k_gather2_write<<<GATHER_GRID, 256, 0, stream>>>(rowptr, ep, z, s2, ss2, (float*)d_out, N, R);
}

// Round 6
// 415.910 us; speedup vs baseline: 1.1133x; 1.1133x over previous
//
#include <hip/hip_runtime.h>

// relationalGraphStack — round 5
// Changes vs R4:
//  - All gathers restructured shuffle-free: one 16-lane column-group per
//    segment (gather2) / per node (gather1), serial in-lane accumulation over
//    the ~2 (resp ~16) edges, 2-way unrolled. No __shfl, no idle write lanes.
//  - ep[k] is a 16-lane broadcast load; z/y1 row loads stay ushort4-coalesced.

#define GATHER_GRID 2048
#define SCAN_CHUNK 4096

typedef short bf16x8 __attribute__((ext_vector_type(8)));
typedef float f32x4 __attribute__((ext_vector_type(4)));

static __device__ __forceinline__ float bf2f(unsigned short u) {
  return __uint_as_float(((unsigned)u) << 16);
}
static __device__ __forceinline__ unsigned short f2bf(float f) {
  unsigned u = __float_as_uint(f);
  u += 0x7FFFu + ((u >> 16) & 1u);  // round to nearest even
  return (unsigned short)(u >> 16);
}

__global__ void k_zero(int* __restrict__ cnt, int n) {
  int i = blockIdx.x * blockDim.x + threadIdx.x;
  int stride = gridDim.x * blockDim.x;
  for (int k = i; k < n; k += stride) cnt[k] = 0;
}

__global__ void k_count(const int* __restrict__ node_out, const int* __restrict__ rel,
                        int* __restrict__ cnt, int E, int R) {
  int i = blockIdx.x * blockDim.x + threadIdx.x;
  int stride = gridDim.x * blockDim.x;
  for (int e = i; e < E; e += stride) {
    atomicAdd(&cnt[node_out[e] * R + rel[e]], 1);
  }
}

__global__ __launch_bounds__(256) void k_scan1(const int* __restrict__ cnt,
                                               int* __restrict__ bsum, int NR) {
  __shared__ int red[256];
  int tid = threadIdx.x;
  int base = blockIdx.x * SCAN_CHUNK;
  int s = 0;
  for (int i = tid; i < SCAN_CHUNK; i += 256) {
    int idx = base + i;
    if (idx < NR) s += cnt[idx];
  }
  red[tid] = s;
  __syncthreads();
  for (int off = 128; off > 0; off >>= 1) {
    if (tid < off) red[tid] += red[tid + off];
    __syncthreads();
  }
  if (tid == 0) bsum[blockIdx.x] = red[0];
}

__global__ void k_scan2(const int* __restrict__ bsum, int* __restrict__ bpre,
                        int* __restrict__ rowptr_end, int NB) {
  int lane = threadIdx.x;
  int carry = 0;
  for (int base = 0; base < NB; base += 64) {
    int i = base + lane;
    int v = (i < NB) ? bsum[i] : 0;
    int incl = v;
    #pragma unroll
    for (int off = 1; off < 64; off <<= 1) {
      int u = __shfl_up(incl, off);
      if (lane >= off) incl += u;
    }
    if (i < NB) bpre[i] = carry + incl - v;
    carry += __shfl(incl, 63);
  }
  if (lane == 0) *rowptr_end = carry;
}

__global__ __launch_bounds__(256) void k_scan3(const int* __restrict__ cnt,
                                               const int* __restrict__ bpre,
                                               int* __restrict__ rowptr,
                                               int* __restrict__ wptr, int NR) {
  __shared__ int wtot[4];
  int tid = threadIdx.x, lane = tid & 63, wid = tid >> 6;
  int base = blockIdx.x * SCAN_CHUNK + tid * 16;
  int v[16];
  int t = 0;
  #pragma unroll
  for (int i = 0; i < 16; i++) {
    int idx = base + i;
    v[i] = (idx < NR) ? cnt[idx] : 0;
    t += v[i];
  }
  int incl = t;
  #pragma unroll
  for (int off = 1; off < 64; off <<= 1) {
    int u = __shfl_up(incl, off);
    if (lane >= off) incl += u;
  }
  if (lane == 63) wtot[wid] = incl;
  __syncthreads();
  int woff = 0;
  for (int w = 0; w < wid; w++) woff += wtot[w];
  int start = bpre[blockIdx.x] + woff + incl - t;
  #pragma unroll
  for (int i = 0; i < 16; i++) {
    int idx = base + i;
    if (idx < NR) { rowptr[idx] = start; wptr[idx] = start; }
    start += v[i];
  }
}

// payload: ep[pos] = (src | rel<<16, RAW w as float bits)   [requires N <= 65536]
__global__ void k_fill(const float* __restrict__ w, const int* __restrict__ node_out,
                       const int* __restrict__ node_in, const int* __restrict__ rel,
                       int* __restrict__ wptr, int2* __restrict__ ep, int E, int R) {
  int i = blockIdx.x * blockDim.x + threadIdx.x;
  int stride = gridDim.x * blockDim.x;
  for (int e = i; e < E; e += stride) {
    int rr = rel[e];
    int seg = node_out[e] * R + rr;
    int pos = atomicAdd(&wptr[seg], 1);
    ep[pos] = make_int2(node_in[e] | (rr << 16), __float_as_int(w[e]));
  }
}

// per-segment weight normalization in-place (no atomics): ep.w /= sum(seg w)
__global__ void k_norm(const int* __restrict__ rowptr, int2* __restrict__ ep, int NR) {
  int s = blockIdx.x * blockDim.x + threadIdx.x;
  if (s >= NR) return;
  int k0 = rowptr[s], k1 = rowptr[s + 1];
  if (k0 >= k1) return;
  float d = 0.f;
  for (int k = k0; k < k1; k++) d += __int_as_float(ep[k].y);
  float inv = 1.f / d;
  for (int k = k0; k < k1; k++) {
    int2 v = ep[k];
    v.y = __float_as_int(__int_as_float(v.y) * inv);
    ep[k] = v;
  }
}

// f32 -> bf16 convert (x)
__global__ void k_f2b(const float4* __restrict__ in, ushort4* __restrict__ out, int n4) {
  int i = blockIdx.x * blockDim.x + threadIdx.x;
  int stride = gridDim.x * blockDim.x;
  for (int k = i; k < n4; k += stride) {
    float4 v = in[k];
    ushort4 o;
    o.x = f2bf(v.x); o.y = f2bf(v.y); o.z = f2bf(v.z); o.w = f2bf(v.w);
    out[k] = o;
  }
}

__global__ void k_packW(const float* __restrict__ Wlin1, const float* __restrict__ Wself1,
                        const float* __restrict__ Wlin2, const float* __restrict__ Wself2,
                        unsigned short* __restrict__ wb1, unsigned short* __restrict__ wb2,
                        int R) {
  int i = blockIdx.x * blockDim.x + threadIdx.x;
  int stride = gridDim.x * blockDim.x;
  int n1 = (R + 1) * 64 * 64;
  int n2 = 2 * 64 * 64;
  for (int k = i; k < n1 + n2; k += stride) {
    if (k < n1) {
      int r = k >> 6, d = k & 63;
      float v;
      if (r < R * 64) {
        int s = r >> 6, j = r & 63;
        v = Wlin1[j * (R * 64) + s * 64 + d];
      } else {
        v = Wself1[(r - R * 64) * 64 + d];
      }
      wb1[k] = f2bf(v);
    } else {
      int k2 = k - n1;
      int r = k2 >> 6, d = k2 & 63;
      float v = (r < 64) ? Wlin2[r * 64 + d] : Wself2[(r - 64) * 64 + d];
      wb2[k2] = f2bf(v);
    }
  }
}

// MFMA GEMM: slabs [0,nslab) -> bf16 outLinB; slab==nslab -> bf16 outSelf.
__global__ __launch_bounds__(256) void k_gemm_mfma(
    const unsigned short* __restrict__ A, int M,
    const unsigned short* __restrict__ Wb, int nslab,
    unsigned short* __restrict__ outLinB, unsigned short* __restrict__ outSelf) {
  int m0 = blockIdx.x * 64;
  int wid = threadIdx.x >> 6;
  int lane = threadIdx.x & 63;
  int mrow = m0 + wid * 16 + (lane & 15);
  int mload = (mrow < M) ? mrow : (M - 1);
  const unsigned short* arow = A + (size_t)mload * 64 + 8 * (lane >> 4);
  bf16x8 a0 = *(const bf16x8*)(arow);
  bf16x8 a1 = *(const bf16x8*)(arow + 32);
  int rbase = m0 + wid * 16 + ((lane >> 4) << 2);
  int cbase = lane & 15;
  for (int slab = 0; slab <= nslab; ++slab) {
    const unsigned short* wrow = Wb + ((size_t)slab * 64 + (lane & 15)) * 64 + 8 * (lane >> 4);
    unsigned short* op = (slab < nslab) ? (outLinB + (size_t)slab * M * 64) : outSelf;
    #pragma unroll
    for (int nt = 0; nt < 4; ++nt) {
      bf16x8 b0 = *(const bf16x8*)(wrow + nt * 16 * 64);
      bf16x8 b1 = *(const bf16x8*)(wrow + nt * 16 * 64 + 32);
      f32x4 c = {};
      c = __builtin_amdgcn_mfma_f32_16x16x32_bf16(a0, b0, c, 0, 0, 0);
      c = __builtin_amdgcn_mfma_f32_16x16x32_bf16(a1, b1, c, 0, 0, 0);
      int col = nt * 16 + cbase;
      #pragma unroll
      for (int rg = 0; rg < 4; ++rg) {
        int grow = rbase + rg;
        if (grow < M) op[(size_t)grow * 64 + col] = f2bf(c[rg]);
      }
    }
  }
}

// layer1 gather, shuffle-free: 16-lane group per node, serial over its edges
// (2-way unrolled). h_pre[n,c] = s1[n,c] + sum w*y1[rel*N+src, c]  (bf16 out)
__global__ __launch_bounds__(256) void k_gather1(
    const int* __restrict__ rowptr, const int2* __restrict__ ep,
    const unsigned short* __restrict__ y1, const unsigned short* __restrict__ s1,
    unsigned short* __restrict__ h_pre, float* __restrict__ part, int N, int R) {
  int lane = threadIdx.x & 63;
  int wid = threadIdx.x >> 6;
  int l16 = lane & 15;
  int lg = lane >> 4;
  int c0 = l16 * 4;
  int grp = blockIdx.x * 16 + wid * 4 + lg;
  int ngrp = gridDim.x * 16;
  float lsum[4] = {0.f, 0.f, 0.f, 0.f}, lsq[4] = {0.f, 0.f, 0.f, 0.f};
  for (int n = grp; n < N; n += ngrp) {
    int k = rowptr[n * R];
    int k1 = rowptr[n * R + R];
    float a0 = 0.f, a1 = 0.f, a2 = 0.f, a3 = 0.f;
    for (; k + 1 < k1; k += 2) {
      int2 pA = ep[k];
      int2 pB = ep[k + 1];
      ushort4 uA = *(const ushort4*)&y1[((size_t)((pA.x >> 16) * N + (pA.x & 0xFFFF))) * 64 + c0];
      ushort4 uB = *(const ushort4*)&y1[((size_t)((pB.x >> 16) * N + (pB.x & 0xFFFF))) * 64 + c0];
      float wA = __int_as_float(pA.y), wB = __int_as_float(pB.y);
      a0 = fmaf(wA, bf2f(uA.x), a0); a1 = fmaf(wA, bf2f(uA.y), a1);
      a2 = fmaf(wA, bf2f(uA.z), a2); a3 = fmaf(wA, bf2f(uA.w), a3);
      a0 = fmaf(wB, bf2f(uB.x), a0); a1 = fmaf(wB, bf2f(uB.y), a1);
      a2 = fmaf(wB, bf2f(uB.z), a2); a3 = fmaf(wB, bf2f(uB.w), a3);
    }
    if (k < k1) {
      int2 p = ep[k];
      float w = __int_as_float(p.y);
      ushort4 u = *(const ushort4*)&y1[((size_t)((p.x >> 16) * N + (p.x & 0xFFFF))) * 64 + c0];
      a0 = fmaf(w, bf2f(u.x), a0); a1 = fmaf(w, bf2f(u.y), a1);
      a2 = fmaf(w, bf2f(u.z), a2); a3 = fmaf(w, bf2f(u.w), a3);
    }
    ushort4 su = *(const ushort4*)&s1[(size_t)n * 64 + c0];
    float v0 = a0 + bf2f(su.x), v1 = a1 + bf2f(su.y);
    float v2 = a2 + bf2f(su.z), v3 = a3 + bf2f(su.w);
    ushort4 o; o.x = f2bf(v0); o.y = f2bf(v1); o.z = f2bf(v2); o.w = f2bf(v3);
    *(ushort4*)&h_pre[(size_t)n * 64 + c0] = o;
    lsum[0] += v0; lsq[0] += v0 * v0;
    lsum[1] += v1; lsq[1] += v1 * v1;
    lsum[2] += v2; lsq[2] += v2 * v2;
    lsum[3] += v3; lsq[3] += v3 * v3;
  }
  __shared__ float sp[16][64], sq[16][64];
  int g = wid * 4 + lg;
  #pragma unroll
  for (int i = 0; i < 4; i++) { sp[g][c0 + i] = lsum[i]; sq[g][c0 + i] = lsq[i]; }
  __syncthreads();
  if (threadIdx.x < 64) {
    int j = threadIdx.x;
    float s = 0.f, q = 0.f;
    #pragma unroll
    for (int gg = 0; gg < 16; gg++) { s += sp[gg][j]; q += sq[gg][j]; }
    part[(size_t)blockIdx.x * 128 + j] = s;
    part[(size_t)blockIdx.x * 128 + 64 + j] = q;
  }
}

// layer2 pass A (stats): 16-lane group per SEGMENT, serial over its ~2 edges.
__global__ __launch_bounds__(256) void k_gather2_stats(
    const int* __restrict__ rowptr, const int2* __restrict__ ep,
    const unsigned short* __restrict__ z, const unsigned short* __restrict__ s2,
    float* __restrict__ part, int N, int R) {
  int lane = threadIdx.x & 63;
  int wid = threadIdx.x >> 6;
  int l16 = lane & 15;
  int lg = lane >> 4;
  int c0 = l16 * 4;
  int grp = blockIdx.x * 16 + wid * 4 + lg;
  int ngrp = gridDim.x * 16;
  int NR = N * R;
  float lsum[4] = {0.f, 0.f, 0.f, 0.f}, lsq[4] = {0.f, 0.f, 0.f, 0.f};
  for (int s = grp; s < NR; s += ngrp) {
    int n = (int)((unsigned)s / (unsigned)R);
    int k = rowptr[s];
    int k1 = rowptr[s + 1];
    float a0 = 0.f, a1 = 0.f, a2 = 0.f, a3 = 0.f;
    for (; k + 1 < k1; k += 2) {
      int2 pA = ep[k];
      int2 pB = ep[k + 1];
      ushort4 uA = *(const ushort4*)&z[(size_t)(pA.x & 0xFFFF) * 64 + c0];
      ushort4 uB = *(const ushort4*)&z[(size_t)(pB.x & 0xFFFF) * 64 + c0];
      float wA = __int_as_float(pA.y), wB = __int_as_float(pB.y);
      a0 = fmaf(wA, bf2f(uA.x), a0); a1 = fmaf(wA, bf2f(uA.y), a1);
      a2 = fmaf(wA, bf2f(uA.z), a2); a3 = fmaf(wA, bf2f(uA.w), a3);
      a0 = fmaf(wB, bf2f(uB.x), a0); a1 = fmaf(wB, bf2f(uB.y), a1);
      a2 = fmaf(wB, bf2f(uB.z), a2); a3 = fmaf(wB, bf2f(uB.w), a3);
    }
    if (k < k1) {
      int2 p = ep[k];
      float w = __int_as_float(p.y);
      ushort4 u = *(const ushort4*)&z[(size_t)(p.x & 0xFFFF) * 64 + c0];
      a0 = fmaf(w, bf2f(u.x), a0); a1 = fmaf(w, bf2f(u.y), a1);
      a2 = fmaf(w, bf2f(u.z), a2); a3 = fmaf(w, bf2f(u.w), a3);
    }
    ushort4 su = *(const ushort4*)&s2[(size_t)n * 64 + c0];
    float v0 = a0 + bf2f(su.x), v1 = a1 + bf2f(su.y);
    float v2 = a2 + bf2f(su.z), v3 = a3 + bf2f(su.w);
    lsum[0] += v0; lsq[0] += v0 * v0;
    lsum[1] += v1; lsq[1] += v1 * v1;
    lsum[2] += v2; lsq[2] += v2 * v2;
    lsum[3] += v3; lsq[3] += v3 * v3;
  }
  __shared__ float sp[16][64], sq[16][64];
  int g = wid * 4 + lg;
  #pragma unroll
  for (int i = 0; i < 4; i++) { sp[g][c0 + i] = lsum[i]; sq[g][c0 + i] = lsq[i]; }
  __syncthreads();
  if (threadIdx.x < 64) {
    int j = threadIdx.x;
    float s = 0.f, q = 0.f;
    #pragma unroll
    for (int gg = 0; gg < 16; gg++) { s += sp[gg][j]; q += sq[gg][j]; }
    part[(size_t)blockIdx.x * 128 + j] = s;
    part[(size_t)blockIdx.x * 128 + 64 + j] = q;
  }
}

// layer2 pass B (write): recompute per segment, normalize, write f32 to d_out.
__global__ __launch_bounds__(256) void k_gather2_write(
    const int* __restrict__ rowptr, const int2* __restrict__ ep,
    const unsigned short* __restrict__ z, const unsigned short* __restrict__ s2,
    const float* __restrict__ ss, float* __restrict__ out, int N, int R) {
  int lane = threadIdx.x & 63;
  int wid = threadIdx.x >> 6;
  int l16 = lane & 15;
  int lg = lane >> 4;
  int c0 = l16 * 4;
  float sc0 = ss[c0], sc1 = ss[c0 + 1], sc2 = ss[c0 + 2], sc3 = ss[c0 + 3];
  float sh0 = ss[64 + c0], sh1 = ss[64 + c0 + 1], sh2 = ss[64 + c0 + 2], sh3 = ss[64 + c0 + 3];
  int grp = blockIdx.x * 16 + wid * 4 + lg;
  int ngrp = gridDim.x * 16;
  int NR = N * R;
  for (int s = grp; s < NR; s += ngrp) {
    int n = (int)((unsigned)s / (unsigned)R);
    int r = s - n * R;
    int k = rowptr[s];
    int k1 = rowptr[s + 1];
    float a0 = 0.f, a1 = 0.f, a2 = 0.f, a3 = 0.f;
    for (; k + 1 < k1; k += 2) {
      int2 pA = ep[k];
      int2 pB = ep[k + 1];
      ushort4 uA = *(const ushort4*)&z[(size_t)(pA.x & 0xFFFF) * 64 + c0];
      ushort4 uB = *(const ushort4*)&z[(size_t)(pB.x & 0xFFFF) * 64 + c0];
      float wA = __int_as_float(pA.y), wB = __int_as_float(pB.y);
      a0 = fmaf(wA, bf2f(uA.x), a0); a1 = fmaf(wA, bf2f(uA.y), a1);
      a2 = fmaf(wA, bf2f(uA.z), a2); a3 = fmaf(wA, bf2f(uA.w), a3);
      a0 = fmaf(wB, bf2f(uB.x), a0); a1 = fmaf(wB, bf2f(uB.y), a1);
      a2 = fmaf(wB, bf2f(uB.z), a2); a3 = fmaf(wB, bf2f(uB.w), a3);
    }
    if (k < k1) {
      int2 p = ep[k];
      float w = __int_as_float(p.y);
      ushort4 u = *(const ushort4*)&z[(size_t)(p.x & 0xFFFF) * 64 + c0];
      a0 = fmaf(w, bf2f(u.x), a0); a1 = fmaf(w, bf2f(u.y), a1);
      a2 = fmaf(w, bf2f(u.z), a2); a3 = fmaf(w, bf2f(u.w), a3);
    }
    ushort4 su = *(const ushort4*)&s2[(size_t)n * 64 + c0];
    float v0 = fmaxf(fmaf(a0 + bf2f(su.x), sc0, sh0), 0.f);
    float v1 = fmaxf(fmaf(a1 + bf2f(su.y), sc1, sh1), 0.f);
    float v2 = fmaxf(fmaf(a2 + bf2f(su.z), sc2, sh2), 0.f);
    float v3 = fmaxf(fmaf(a3 + bf2f(su.w), sc3, sh3), 0.f);
    *(float4*)&out[((size_t)r * N + n) * 64 + c0] = make_float4(v0, v1, v2, v3);
  }
}

__global__ __launch_bounds__(1024) void k_bnstats(
    const float* __restrict__ part, int P, float M,
    const float* __restrict__ gamma, const float* __restrict__ beta,
    float* __restrict__ ss) {
  __shared__ float red[1024];
  int tid = threadIdx.x;
  int j = tid & 127;
  int g = tid >> 7;
  float acc = 0.f;
  for (int i = g; i < P; i += 8) acc += part[(size_t)i * 128 + j];
  red[tid] = acc;
  __syncthreads();
  if (tid < 128) {
    float s = 0.f;
    for (int gg = 0; gg < 8; gg++) s += red[gg * 128 + tid];
    red[tid] = s;
  }
  __syncthreads();
  if (tid < 64) {
    float s = red[tid], q = red[64 + tid];
    float mean = s / M;
    float var = q / M - mean * mean;
    float sc = gamma[tid] / sqrtf(var + 1e-5f);
    ss[tid] = sc;
    ss[64 + tid] = beta[tid] - mean * sc;
  }
}

// bn+relu, bf16 in -> bf16 out (h_pre -> h)
__global__ void k_bnrelu_b2b(const ushort4* __restrict__ in, ushort4* __restrict__ out,
                             const float* __restrict__ ss, long total4) {
  __shared__ float s_ss[128];
  if (threadIdx.x < 128) s_ss[threadIdx.x] = ss[threadIdx.x];
  __syncthreads();
  long i = (long)blockIdx.x * blockDim.x + threadIdx.x;
  long stride = (long)gridDim.x * blockDim.x;
  for (long k = i; k < total4; k += stride) {
    ushort4 v = in[k];
    int j0 = ((int)k & 15) * 4;
    ushort4 o;
    o.x = f2bf(fmaxf(fmaf(bf2f(v.x), s_ss[j0 + 0], s_ss[64 + j0 + 0]), 0.f));
    o.y = f2bf(fmaxf(fmaf(bf2f(v.y), s_ss[j0 + 1], s_ss[64 + j0 + 1]), 0.f));
    o.z = f2bf(fmaxf(fmaf(bf2f(v.z), s_ss[j0 + 2], s_ss[64 + j0 + 2]), 0.f));
    o.w = f2bf(fmaxf(fmaf(bf2f(v.w), s_ss[j0 + 3], s_ss[64 + j0 + 3]), 0.f));
    out[k] = o;
  }
}

extern "C" void kernel_launch(void* const* d_in, const int* in_sizes, int n_in,
                              void* d_out, int out_size, void* d_ws, size_t ws_size,
                              hipStream_t stream) {
  const float* x        = (const float*)d_in[0];
  const float* edge_w   = (const float*)d_in[1];
  const float* W_lin1   = (const float*)d_in[2];
  const float* W_self1  = (const float*)d_in[4];
  const float* gamma1   = (const float*)d_in[6];
  const float* beta1    = (const float*)d_in[7];
  const float* W_lin2   = (const float*)d_in[8];
  const float* W_self2  = (const float*)d_in[10];
  const float* gamma2   = (const float*)d_in[12];
  const float* beta2    = (const float*)d_in[13];
  const int* node_in    = (const int*)d_in[14];
  const int* node_out   = (const int*)d_in[15];
  const int* relation   = (const int*)d_in[16];

  int N = in_sizes[0] / 64;           // 50000
  int E = in_sizes[1];                // 800000
  int R = in_sizes[2] / (64 * 64);    // 8
  int NR = N * R;
  int NB = (NR + SCAN_CHUNK - 1) / SCAN_CHUNK;

  char* p = (char*)d_ws;
  auto alloc = [&](size_t bytes) { char* r = p; p += (bytes + 255) & ~(size_t)255; return r; };
  int* cnt      = (int*)alloc(4ull * NR);
  int* rowptr   = (int*)alloc(4ull * (NR + 1));
  int* wptr     = (int*)alloc(4ull * NR);
  int* bsum     = (int*)alloc(4ull * NB);
  int* bpre     = (int*)alloc(4ull * NB);
  int2* ep      = (int2*)alloc(8ull * E);
  unsigned short* wb1 = (unsigned short*)alloc(2ull * (R + 1) * 64 * 64);
  unsigned short* wb2 = (unsigned short*)alloc(2ull * 2 * 64 * 64);
  unsigned short* s1    = (unsigned short*)alloc(2ull * N * 64);
  unsigned short* h_pre = (unsigned short*)alloc(2ull * N * 64);
  unsigned short* z     = (unsigned short*)alloc(2ull * N * 64);
  unsigned short* s2    = (unsigned short*)alloc(2ull * N * 64);
  float* part   = (float*)alloc(4ull * GATHER_GRID * 128);
  float* ss1    = (float*)alloc(4ull * 128);
  float* ss2    = (float*)alloc(4ull * 128);

  // d_out scratch: y1 bf16 [0, 51.2MB), xb, hb after (all dead before pass B writes).
  unsigned short* y1 = (unsigned short*)d_out;
  unsigned short* xb = (unsigned short*)((char*)d_out + 2ull * R * N * 64);
  unsigned short* hb = xb + (size_t)N * 64;

  k_zero<<<512, 256, 0, stream>>>(cnt, NR);
  k_count<<<2048, 256, 0, stream>>>(node_out, relation, cnt, E, R);
  k_scan1<<<NB, 256, 0, stream>>>(cnt, bsum, NR);
  k_scan2<<<1, 64, 0, stream>>>(bsum, bpre, &rowptr[NR], NB);
  k_scan3<<<NB, 256, 0, stream>>>(cnt, bpre, rowptr, wptr, NR);
  k_fill<<<2048, 256, 0, stream>>>(edge_w, node_out, node_in, relation, wptr, ep, E, R);
  k_norm<<<(NR + 255) / 256, 256, 0, stream>>>(rowptr, ep, NR);

  k_f2b<<<1024, 256, 0, stream>>>((const float4*)x, (ushort4*)xb, N * 64 / 4);
  k_packW<<<64, 256, 0, stream>>>(W_lin1, W_self1, W_lin2, W_self2, wb1, wb2, R);

  // layer 1
  int mblocks = (N + 63) / 64;
  k_gemm_mfma<<<mblocks, 256, 0, stream>>>(xb, N, wb1, R, y1, s1);
  k_gather1<<<GATHER_GRID, 256, 0, stream>>>(rowptr, ep, y1, s1, h_pre, part, N, R);
  k_bnstats<<<1, 1024, 0, stream>>>(part, GATHER_GRID, (float)N, gamma1, beta1, ss1);
  k_bnrelu_b2b<<<2048, 256, 0, stream>>>((const ushort4*)h_pre, (ushort4*)hb, ss1, (long)N * 64 / 4);

  // layer 2: stats pass -> bnstats -> normalize-write pass
  k_gemm_mfma<<<mblocks, 256, 0, stream>>>(hb, N, wb2, 1, z, s2);
  k_gather2_stats<<<GATHER_GRID, 256, 0, stream>>>(rowptr, ep, z, s2, part, N, R);
  k_bnstats<<<1, 1024, 0, stream>>>(part, GATHER_GRID, (float)N * R, gamma2, beta2, ss2);
  k_gather2_write<<<GATHER_GRID, 256, 0, stream>>>(rowptr, ep, z, s2, ss2, (float*)d_out, N, R);
}

// Round 7
// 300.313 us; speedup vs baseline: 1.5419x; 1.3849x over previous
//
#include <hip/hip_runtime.h>

// relationalGraphStack — round 6
// Changes vs R5:
//  - k_bnstats was a single-block latency trap (70us x2 = 1/3 of runtime,
//    0.17% occupancy, serial 256-deep dependent load chain). Replaced by
//    two-stage reduction: k_red1 (64 blocks, coalesced, ~5us) -> k_bnstats
//    over 64 rows (~4us). Deterministic fixed-order summation.

#define GATHER_GRID 2048
#define SCAN_CHUNK 4096
#define RED_BLOCKS 64

typedef short bf16x8 __attribute__((ext_vector_type(8)));
typedef float f32x4 __attribute__((ext_vector_type(4)));

static __device__ __forceinline__ float bf2f(unsigned short u) {
  return __uint_as_float(((unsigned)u) << 16);
}
static __device__ __forceinline__ unsigned short f2bf(float f) {
  unsigned u = __float_as_uint(f);
  u += 0x7FFFu + ((u >> 16) & 1u);  // round to nearest even
  return (unsigned short)(u >> 16);
}

__global__ void k_zero(int* __restrict__ cnt, int n) {
  int i = blockIdx.x * blockDim.x + threadIdx.x;
  int stride = gridDim.x * blockDim.x;
  for (int k = i; k < n; k += stride) cnt[k] = 0;
}

__global__ void k_count(const int* __restrict__ node_out, const int* __restrict__ rel,
                        int* __restrict__ cnt, int E, int R) {
  int i = blockIdx.x * blockDim.x + threadIdx.x;
  int stride = gridDim.x * blockDim.x;
  for (int e = i; e < E; e += stride) {
    atomicAdd(&cnt[node_out[e] * R + rel[e]], 1);
  }
}

__global__ __launch_bounds__(256) void k_scan1(const int* __restrict__ cnt,
                                               int* __restrict__ bsum, int NR) {
  __shared__ int red[256];
  int tid = threadIdx.x;
  int base = blockIdx.x * SCAN_CHUNK;
  int s = 0;
  for (int i = tid; i < SCAN_CHUNK; i += 256) {
    int idx = base + i;
    if (idx < NR) s += cnt[idx];
  }
  red[tid] = s;
  __syncthreads();
  for (int off = 128; off > 0; off >>= 1) {
    if (tid < off) red[tid] += red[tid + off];
    __syncthreads();
  }
  if (tid == 0) bsum[blockIdx.x] = red[0];
}

__global__ void k_scan2(const int* __restrict__ bsum, int* __restrict__ bpre,
                        int* __restrict__ rowptr_end, int NB) {
  int lane = threadIdx.x;
  int carry = 0;
  for (int base = 0; base < NB; base += 64) {
    int i = base + lane;
    int v = (i < NB) ? bsum[i] : 0;
    int incl = v;
    #pragma unroll
    for (int off = 1; off < 64; off <<= 1) {
      int u = __shfl_up(incl, off);
      if (lane >= off) incl += u;
    }
    if (i < NB) bpre[i] = carry + incl - v;
    carry += __shfl(incl, 63);
  }
  if (lane == 0) *rowptr_end = carry;
}

__global__ __launch_bounds__(256) void k_scan3(const int* __restrict__ cnt,
                                               const int* __restrict__ bpre,
                                               int* __restrict__ rowptr,
                                               int* __restrict__ wptr, int NR) {
  __shared__ int wtot[4];
  int tid = threadIdx.x, lane = tid & 63, wid = tid >> 6;
  int base = blockIdx.x * SCAN_CHUNK + tid * 16;
  int v[16];
  int t = 0;
  #pragma unroll
  for (int i = 0; i < 16; i++) {
    int idx = base + i;
    v[i] = (idx < NR) ? cnt[idx] : 0;
    t += v[i];
  }
  int incl = t;
  #pragma unroll
  for (int off = 1; off < 64; off <<= 1) {
    int u = __shfl_up(incl, off);
    if (lane >= off) incl += u;
  }
  if (lane == 63) wtot[wid] = incl;
  __syncthreads();
  int woff = 0;
  for (int w = 0; w < wid; w++) woff += wtot[w];
  int start = bpre[blockIdx.x] + woff + incl - t;
  #pragma unroll
  for (int i = 0; i < 16; i++) {
    int idx = base + i;
    if (idx < NR) { rowptr[idx] = start; wptr[idx] = start; }
    start += v[i];
  }
}

// payload: ep[pos] = (src | rel<<16, RAW w as float bits)   [requires N <= 65536]
__global__ void k_fill(const float* __restrict__ w, const int* __restrict__ node_out,
                       const int* __restrict__ node_in, const int* __restrict__ rel,
                       int* __restrict__ wptr, int2* __restrict__ ep, int E, int R) {
  int i = blockIdx.x * blockDim.x + threadIdx.x;
  int stride = gridDim.x * blockDim.x;
  for (int e = i; e < E; e += stride) {
    int rr = rel[e];
    int seg = node_out[e] * R + rr;
    int pos = atomicAdd(&wptr[seg], 1);
    ep[pos] = make_int2(node_in[e] | (rr << 16), __float_as_int(w[e]));
  }
}

// per-segment weight normalization in-place (no atomics): ep.w /= sum(seg w)
__global__ void k_norm(const int* __restrict__ rowptr, int2* __restrict__ ep, int NR) {
  int s = blockIdx.x * blockDim.x + threadIdx.x;
  if (s >= NR) return;
  int k0 = rowptr[s], k1 = rowptr[s + 1];
  if (k0 >= k1) return;
  float d = 0.f;
  for (int k = k0; k < k1; k++) d += __int_as_float(ep[k].y);
  float inv = 1.f / d;
  for (int k = k0; k < k1; k++) {
    int2 v = ep[k];
    v.y = __float_as_int(__int_as_float(v.y) * inv);
    ep[k] = v;
  }
}

// f32 -> bf16 convert (x)
__global__ void k_f2b(const float4* __restrict__ in, ushort4* __restrict__ out, int n4) {
  int i = blockIdx.x * blockDim.x + threadIdx.x;
  int stride = gridDim.x * blockDim.x;
  for (int k = i; k < n4; k += stride) {
    float4 v = in[k];
    ushort4 o;
    o.x = f2bf(v.x); o.y = f2bf(v.y); o.z = f2bf(v.z); o.w = f2bf(v.w);
    out[k] = o;
  }
}

__global__ void k_packW(const float* __restrict__ Wlin1, const float* __restrict__ Wself1,
                        const float* __restrict__ Wlin2, const float* __restrict__ Wself2,
                        unsigned short* __restrict__ wb1, unsigned short* __restrict__ wb2,
                        int R) {
  int i = blockIdx.x * blockDim.x + threadIdx.x;
  int stride = gridDim.x * blockDim.x;
  int n1 = (R + 1) * 64 * 64;
  int n2 = 2 * 64 * 64;
  for (int k = i; k < n1 + n2; k += stride) {
    if (k < n1) {
      int r = k >> 6, d = k & 63;
      float v;
      if (r < R * 64) {
        int s = r >> 6, j = r & 63;
        v = Wlin1[j * (R * 64) + s * 64 + d];
      } else {
        v = Wself1[(r - R * 64) * 64 + d];
      }
      wb1[k] = f2bf(v);
    } else {
      int k2 = k - n1;
      int r = k2 >> 6, d = k2 & 63;
      float v = (r < 64) ? Wlin2[r * 64 + d] : Wself2[(r - 64) * 64 + d];
      wb2[k2] = f2bf(v);
    }
  }
}

// MFMA GEMM: slabs [0,nslab) -> bf16 outLinB; slab==nslab -> bf16 outSelf.
__global__ __launch_bounds__(256) void k_gemm_mfma(
    const unsigned short* __restrict__ A, int M,
    const unsigned short* __restrict__ Wb, int nslab,
    unsigned short* __restrict__ outLinB, unsigned short* __restrict__ outSelf) {
  int m0 = blockIdx.x * 64;
  int wid = threadIdx.x >> 6;
  int lane = threadIdx.x & 63;
  int mrow = m0 + wid * 16 + (lane & 15);
  int mload = (mrow < M) ? mrow : (M - 1);
  const unsigned short* arow = A + (size_t)mload * 64 + 8 * (lane >> 4);
  bf16x8 a0 = *(const bf16x8*)(arow);
  bf16x8 a1 = *(const bf16x8*)(arow + 32);
  int rbase = m0 + wid * 16 + ((lane >> 4) << 2);
  int cbase = lane & 15;
  for (int slab = 0; slab <= nslab; ++slab) {
    const unsigned short* wrow = Wb + ((size_t)slab * 64 + (lane & 15)) * 64 + 8 * (lane >> 4);
    unsigned short* op = (slab < nslab) ? (outLinB + (size_t)slab * M * 64) : outSelf;
    #pragma unroll
    for (int nt = 0; nt < 4; ++nt) {
      bf16x8 b0 = *(const bf16x8*)(wrow + nt * 16 * 64);
      bf16x8 b1 = *(const bf16x8*)(wrow + nt * 16 * 64 + 32);
      f32x4 c = {};
      c = __builtin_amdgcn_mfma_f32_16x16x32_bf16(a0, b0, c, 0, 0, 0);
      c = __builtin_amdgcn_mfma_f32_16x16x32_bf16(a1, b1, c, 0, 0, 0);
      int col = nt * 16 + cbase;
      #pragma unroll
      for (int rg = 0; rg < 4; ++rg) {
        int grow = rbase + rg;
        if (grow < M) op[(size_t)grow * 64 + col] = f2bf(c[rg]);
      }
    }
  }
}

// layer1 gather, shuffle-free: 16-lane group per node, serial over its edges
__global__ __launch_bounds__(256) void k_gather1(
    const int* __restrict__ rowptr, const int2* __restrict__ ep,
    const unsigned short* __restrict__ y1, const unsigned short* __restrict__ s1,
    unsigned short* __restrict__ h_pre, float* __restrict__ part, int N, int R) {
  int lane = threadIdx.x & 63;
  int wid = threadIdx.x >> 6;
  int l16 = lane & 15;
  int lg = lane >> 4;
  int c0 = l16 * 4;
  int grp = blockIdx.x * 16 + wid * 4 + lg;
  int ngrp = gridDim.x * 16;
  float lsum[4] = {0.f, 0.f, 0.f, 0.f}, lsq[4] = {0.f, 0.f, 0.f, 0.f};
  for (int n = grp; n < N; n += ngrp) {
    int k = rowptr[n * R];
    int k1 = rowptr[n * R + R];
    float a0 = 0.f, a1 = 0.f, a2 = 0.f, a3 = 0.f;
    for (; k + 1 < k1; k += 2) {
      int2 pA = ep[k];
      int2 pB = ep[k + 1];
      ushort4 uA = *(const ushort4*)&y1[((size_t)((pA.x >> 16) * N + (pA.x & 0xFFFF))) * 64 + c0];
      ushort4 uB = *(const ushort4*)&y1[((size_t)((pB.x >> 16) * N + (pB.x & 0xFFFF))) * 64 + c0];
      float wA = __int_as_float(pA.y), wB = __int_as_float(pB.y);
      a0 = fmaf(wA, bf2f(uA.x), a0); a1 = fmaf(wA, bf2f(uA.y), a1);
      a2 = fmaf(wA, bf2f(uA.z), a2); a3 = fmaf(wA, bf2f(uA.w), a3);
      a0 = fmaf(wB, bf2f(uB.x), a0); a1 = fmaf(wB, bf2f(uB.y), a1);
      a2 = fmaf(wB, bf2f(uB.z), a2); a3 = fmaf(wB, bf2f(uB.w), a3);
    }
    if (k < k1) {
      int2 p = ep[k];
      float w = __int_as_float(p.y);
      ushort4 u = *(const ushort4*)&y1[((size_t)((p.x >> 16) * N + (p.x & 0xFFFF))) * 64 + c0];
      a0 = fmaf(w, bf2f(u.x), a0); a1 = fmaf(w, bf2f(u.y), a1);
      a2 = fmaf(w, bf2f(u.z), a2); a3 = fmaf(w, bf2f(u.w), a3);
    }
    ushort4 su = *(const ushort4*)&s1[(size_t)n * 64 + c0];
    float v0 = a0 + bf2f(su.x), v1 = a1 + bf2f(su.y);
    float v2 = a2 + bf2f(su.z), v3 = a3 + bf2f(su.w);
    ushort4 o; o.x = f2bf(v0); o.y = f2bf(v1); o.z = f2bf(v2); o.w = f2bf(v3);
    *(ushort4*)&h_pre[(size_t)n * 64 + c0] = o;
    lsum[0] += v0; lsq[0] += v0 * v0;
    lsum[1] += v1; lsq[1] += v1 * v1;
    lsum[2] += v2; lsq[2] += v2 * v2;
    lsum[3] += v3; lsq[3] += v3 * v3;
  }
  __shared__ float sp[16][64], sq[16][64];
  int g = wid * 4 + lg;
  #pragma unroll
  for (int i = 0; i < 4; i++) { sp[g][c0 + i] = lsum[i]; sq[g][c0 + i] = lsq[i]; }
  __syncthreads();
  if (threadIdx.x < 64) {
    int j = threadIdx.x;
    float s = 0.f, q = 0.f;
    #pragma unroll
    for (int gg = 0; gg < 16; gg++) { s += sp[gg][j]; q += sq[gg][j]; }
    part[(size_t)blockIdx.x * 128 + j] = s;
    part[(size_t)blockIdx.x * 128 + 64 + j] = q;
  }
}

// layer2 pass A (stats): 16-lane group per SEGMENT, serial over its ~2 edges.
__global__ __launch_bounds__(256) void k_gather2_stats(
    const int* __restrict__ rowptr, const int2* __restrict__ ep,
    const unsigned short* __restrict__ z, const unsigned short* __restrict__ s2,
    float* __restrict__ part, int N, int R) {
  int lane = threadIdx.x & 63;
  int wid = threadIdx.x >> 6;
  int l16 = lane & 15;
  int lg = lane >> 4;
  int c0 = l16 * 4;
  int grp = blockIdx.x * 16 + wid * 4 + lg;
  int ngrp = gridDim.x * 16;
  int NR = N * R;
  float lsum[4] = {0.f, 0.f, 0.f, 0.f}, lsq[4] = {0.f, 0.f, 0.f, 0.f};
  for (int s = grp; s < NR; s += ngrp) {
    int n = (int)((unsigned)s / (unsigned)R);
    int k = rowptr[s];
    int k1 = rowptr[s + 1];
    float a0 = 0.f, a1 = 0.f, a2 = 0.f, a3 = 0.f;
    for (; k + 1 < k1; k += 2) {
      int2 pA = ep[k];
      int2 pB = ep[k + 1];
      ushort4 uA = *(const ushort4*)&z[(size_t)(pA.x & 0xFFFF) * 64 + c0];
      ushort4 uB = *(const ushort4*)&z[(size_t)(pB.x & 0xFFFF) * 64 + c0];
      float wA = __int_as_float(pA.y), wB = __int_as_float(pB.y);
      a0 = fmaf(wA, bf2f(uA.x), a0); a1 = fmaf(wA, bf2f(uA.y), a1);
      a2 = fmaf(wA, bf2f(uA.z), a2); a3 = fmaf(wA, bf2f(uA.w), a3);
      a0 = fmaf(wB, bf2f(uB.x), a0); a1 = fmaf(wB, bf2f(uB.y), a1);
      a2 = fmaf(wB, bf2f(uB.z), a2); a3 = fmaf(wB, bf2f(uB.w), a3);
    }
    if (k < k1) {
      int2 p = ep[k];
      float w = __int_as_float(p.y);
      ushort4 u = *(const ushort4*)&z[(size_t)(p.x & 0xFFFF) * 64 + c0];
      a0 = fmaf(w, bf2f(u.x), a0); a1 = fmaf(w, bf2f(u.y), a1);
      a2 = fmaf(w, bf2f(u.z), a2); a3 = fmaf(w, bf2f(u.w), a3);
    }
    ushort4 su = *(const ushort4*)&s2[(size_t)n * 64 + c0];
    float v0 = a0 + bf2f(su.x), v1 = a1 + bf2f(su.y);
    float v2 = a2 + bf2f(su.z), v3 = a3 + bf2f(su.w);
    lsum[0] += v0; lsq[0] += v0 * v0;
    lsum[1] += v1; lsq[1] += v1 * v1;
    lsum[2] += v2; lsq[2] += v2 * v2;
    lsum[3] += v3; lsq[3] += v3 * v3;
  }
  __shared__ float sp[16][64], sq[16][64];
  int g = wid * 4 + lg;
  #pragma unroll
  for (int i = 0; i < 4; i++) { sp[g][c0 + i] = lsum[i]; sq[g][c0 + i] = lsq[i]; }
  __syncthreads();
  if (threadIdx.x < 64) {
    int j = threadIdx.x;
    float s = 0.f, q = 0.f;
    #pragma unroll
    for (int gg = 0; gg < 16; gg++) { s += sp[gg][j]; q += sq[gg][j]; }
    part[(size_t)blockIdx.x * 128 + j] = s;
    part[(size_t)blockIdx.x * 128 + 64 + j] = q;
  }
}

// layer2 pass B (write): recompute per segment, normalize, write f32 to d_out.
__global__ __launch_bounds__(256) void k_gather2_write(
    const int* __restrict__ rowptr, const int2* __restrict__ ep,
    const unsigned short* __restrict__ z, const unsigned short* __restrict__ s2,
    const float* __restrict__ ss, float* __restrict__ out, int N, int R) {
  int lane = threadIdx.x & 63;
  int wid = threadIdx.x >> 6;
  int l16 = lane & 15;
  int lg = lane >> 4;
  int c0 = l16 * 4;
  float sc0 = ss[c0], sc1 = ss[c0 + 1], sc2 = ss[c0 + 2], sc3 = ss[c0 + 3];
  float sh0 = ss[64 + c0], sh1 = ss[64 + c0 + 1], sh2 = ss[64 + c0 + 2], sh3 = ss[64 + c0 + 3];
  int grp = blockIdx.x * 16 + wid * 4 + lg;
  int ngrp = gridDim.x * 16;
  int NR = N * R;
  for (int s = grp; s < NR; s += ngrp) {
    int n = (int)((unsigned)s / (unsigned)R);
    int r = s - n * R;
    int k = rowptr[s];
    int k1 = rowptr[s + 1];
    float a0 = 0.f, a1 = 0.f, a2 = 0.f, a3 = 0.f;
    for (; k + 1 < k1; k += 2) {
      int2 pA = ep[k];
      int2 pB = ep[k + 1];
      ushort4 uA = *(const ushort4*)&z[(size_t)(pA.x & 0xFFFF) * 64 + c0];
      ushort4 uB = *(const ushort4*)&z[(size_t)(pB.x & 0xFFFF) * 64 + c0];
      float wA = __int_as_float(pA.y), wB = __int_as_float(pB.y);
      a0 = fmaf(wA, bf2f(uA.x), a0); a1 = fmaf(wA, bf2f(uA.y), a1);
      a2 = fmaf(wA, bf2f(uA.z), a2); a3 = fmaf(wA, bf2f(uA.w), a3);
      a0 = fmaf(wB, bf2f(uB.x), a0); a1 = fmaf(wB, bf2f(uB.y), a1);
      a2 = fmaf(wB, bf2f(uB.z), a2); a3 = fmaf(wB, bf2f(uB.w), a3);
    }
    if (k < k1) {
      int2 p = ep[k];
      float w = __int_as_float(p.y);
      ushort4 u = *(const ushort4*)&z[(size_t)(p.x & 0xFFFF) * 64 + c0];
      a0 = fmaf(w, bf2f(u.x), a0); a1 = fmaf(w, bf2f(u.y), a1);
      a2 = fmaf(w, bf2f(u.z), a2); a3 = fmaf(w, bf2f(u.w), a3);
    }
    ushort4 su = *(const ushort4*)&s2[(size_t)n * 64 + c0];
    float v0 = fmaxf(fmaf(a0 + bf2f(su.x), sc0, sh0), 0.f);
    float v1 = fmaxf(fmaf(a1 + bf2f(su.y), sc1, sh1), 0.f);
    float v2 = fmaxf(fmaf(a2 + bf2f(su.z), sc2, sh2), 0.f);
    float v3 = fmaxf(fmaf(a3 + bf2f(su.w), sc3, sh3), 0.f);
    *(float4*)&out[((size_t)r * N + n) * 64 + c0] = make_float4(v0, v1, v2, v3);
  }
}

// stage 1: reduce part[GATHER_GRID][128] -> part2[RED_BLOCKS][128] (coalesced, parallel)
__global__ __launch_bounds__(256) void k_red1(const float* __restrict__ part,
                                              float* __restrict__ part2, int P) {
  int j = threadIdx.x & 127;
  int g = threadIdx.x >> 7;           // 0 or 1
  int rows = P / RED_BLOCKS;          // 32
  int base = blockIdx.x * rows;
  float acc = 0.f;
  for (int i = g; i < rows; i += 2) acc += part[(size_t)(base + i) * 128 + j];
  __shared__ float red[2][128];
  red[g][j] = acc;
  __syncthreads();
  if (threadIdx.x < 128) part2[(size_t)blockIdx.x * 128 + j] = red[0][j] + red[1][j];
}

// stage 2: 64 rows -> scale/shift
__global__ __launch_bounds__(1024) void k_bnstats(
    const float* __restrict__ part, int P, float M,
    const float* __restrict__ gamma, const float* __restrict__ beta,
    float* __restrict__ ss) {
  __shared__ float red[1024];
  int tid = threadIdx.x;
  int j = tid & 127;
  int g = tid >> 7;
  float acc = 0.f;
  for (int i = g; i < P; i += 8) acc += part[(size_t)i * 128 + j];
  red[tid] = acc;
  __syncthreads();
  if (tid < 128) {
    float s = 0.f;
    for (int gg = 0; gg < 8; gg++) s += red[gg * 128 + tid];
    red[tid] = s;
  }
  __syncthreads();
  if (tid < 64) {
    float s = red[tid], q = red[64 + tid];
    float mean = s / M;
    float var = q / M - mean * mean;
    float sc = gamma[tid] / sqrtf(var + 1e-5f);
    ss[tid] = sc;
    ss[64 + tid] = beta[tid] - mean * sc;
  }
}

// bn+relu, bf16 in -> bf16 out (h_pre -> h)
__global__ void k_bnrelu_b2b(const ushort4* __restrict__ in, ushort4* __restrict__ out,
                             const float* __restrict__ ss, long total4) {
  __shared__ float s_ss[128];
  if (threadIdx.x < 128) s_ss[threadIdx.x] = ss[threadIdx.x];
  __syncthreads();
  long i = (long)blockIdx.x * blockDim.x + threadIdx.x;
  long stride = (long)gridDim.x * blockDim.x;
  for (long k = i; k < total4; k += stride) {
    ushort4 v = in[k];
    int j0 = ((int)k & 15) * 4;
    ushort4 o;
    o.x = f2bf(fmaxf(fmaf(bf2f(v.x), s_ss[j0 + 0], s_ss[64 + j0 + 0]), 0.f));
    o.y = f2bf(fmaxf(fmaf(bf2f(v.y), s_ss[j0 + 1], s_ss[64 + j0 + 1]), 0.f));
    o.z = f2bf(fmaxf(fmaf(bf2f(v.z), s_ss[j0 + 2], s_ss[64 + j0 + 2]), 0.f));
    o.w = f2bf(fmaxf(fmaf(bf2f(v.w), s_ss[j0 + 3], s_ss[64 + j0 + 3]), 0.f));
    out[k] = o;
  }
}

extern "C" void kernel_launch(void* const* d_in, const int* in_sizes, int n_in,
                              void* d_out, int out_size, void* d_ws, size_t ws_size,
                              hipStream_t stream) {
  const float* x        = (const float*)d_in[0];
  const float* edge_w   = (const float*)d_in[1];
  const float* W_lin1   = (const float*)d_in[2];
  const float* W_self1  = (const float*)d_in[4];
  const float* gamma1   = (const float*)d_in[6];
  const float* beta1    = (const float*)d_in[7];
  const float* W_lin2   = (const float*)d_in[8];
  const float* W_self2  = (const float*)d_in[10];
  const float* gamma2   = (const float*)d_in[12];
  const float* beta2    = (const float*)d_in[13];
  const int* node_in    = (const int*)d_in[14];
  const int* node_out   = (const int*)d_in[15];
  const int* relation   = (const int*)d_in[16];

  int N = in_sizes[0] / 64;           // 50000
  int E = in_sizes[1];                // 800000
  int R = in_sizes[2] / (64 * 64);    // 8
  int NR = N * R;
  int NB = (NR + SCAN_CHUNK - 1) / SCAN_CHUNK;

  char* p = (char*)d_ws;
  auto alloc = [&](size_t bytes) { char* r = p; p += (bytes + 255) & ~(size_t)255; return r; };
  int* cnt      = (int*)alloc(4ull * NR);
  int* rowptr   = (int*)alloc(4ull * (NR + 1));
  int* wptr     = (int*)alloc(4ull * NR);
  int* bsum     = (int*)alloc(4ull * NB);
  int* bpre     = (int*)alloc(4ull * NB);
  int2* ep      = (int2*)alloc(8ull * E);
  unsigned short* wb1 = (unsigned short*)alloc(2ull * (R + 1) * 64 * 64);
  unsigned short* wb2 = (unsigned short*)alloc(2ull * 2 * 64 * 64);
  unsigned short* s1    = (unsigned short*)alloc(2ull * N * 64);
  unsigned short* h_pre = (unsigned short*)alloc(2ull * N * 64);
  unsigned short* z     = (unsigned short*)alloc(2ull * N * 64);
  unsigned short* s2    = (unsigned short*)alloc(2ull * N * 64);
  float* part   = (float*)alloc(4ull * GATHER_GRID * 128);
  float* part2  = (float*)alloc(4ull * RED_BLOCKS * 128);
  float* ss1    = (float*)alloc(4ull * 128);
  float* ss2    = (float*)alloc(4ull * 128);

  // d_out scratch: y1 bf16 [0, 51.2MB), xb, hb after (all dead before pass B writes).
  unsigned short* y1 = (unsigned short*)d_out;
  unsigned short* xb = (unsigned short*)((char*)d_out + 2ull * R * N * 64);
  unsigned short* hb = xb + (size_t)N * 64;

  k_zero<<<512, 256, 0, stream>>>(cnt, NR);
  k_count<<<2048, 256, 0, stream>>>(node_out, relation, cnt, E, R);
  k_scan1<<<NB, 256, 0, stream>>>(cnt, bsum, NR);
  k_scan2<<<1, 64, 0, stream>>>(bsum, bpre, &rowptr[NR], NB);
  k_scan3<<<NB, 256, 0, stream>>>(cnt, bpre, rowptr, wptr, NR);
  k_fill<<<2048, 256, 0, stream>>>(edge_w, node_out, node_in, relation, wptr, ep, E, R);
  k_norm<<<(NR + 255) / 256, 256, 0, stream>>>(rowptr, ep, NR);

  k_f2b<<<1024, 256, 0, stream>>>((const float4*)x, (ushort4*)xb, N * 64 / 4);
  k_packW<<<64, 256, 0, stream>>>(W_lin1, W_self1, W_lin2, W_self2, wb1, wb2, R);

  // layer 1
  int mblocks = (N + 63) / 64;
  k_gemm_mfma<<<mblocks, 256, 0, stream>>>(xb, N, wb1, R, y1, s1);
  k_gather1<<<GATHER_GRID, 256, 0, stream>>>(rowptr, ep, y1, s1, h_pre, part, N, R);
  k_red1<<<RED_BLOCKS, 256, 0, stream>>>(part, part2, GATHER_GRID);
  k_bnstats<<<1, 1024, 0, stream>>>(part2, RED_BLOCKS, (float)N, gamma1, beta1, ss1);
  k_bnrelu_b2b<<<2048, 256, 0, stream>>>((const ushort4*)h_pre, (ushort4*)hb, ss1, (long)N * 64 / 4);

  // layer 2: stats pass -> reduce -> bnstats -> normalize-write pass
  k_gemm_mfma<<<mblocks, 256, 0, stream>>>(hb, N, wb2, 1, z, s2);
  k_gather2_stats<<<GATHER_GRID, 256, 0, stream>>>(rowptr, ep, z, s2, part, N, R);
  k_red1<<<RED_BLOCKS, 256, 0, stream>>>(part, part2, GATHER_GRID);
  k_bnstats<<<1, 1024, 0, stream>>>(part2, RED_BLOCKS, (float)N * R, gamma2, beta2, ss2);
  k_gather2_write<<<GATHER_GRID, 256, 0, stream>>>(rowptr, ep, z, s2, ss2, (float*)d_out, N, R);
}

// Round 8
// 257.698 us; speedup vs baseline: 1.7969x; 1.1654x over previous
//
#include <hip/hip_runtime.h>

// relationalGraphStack — round 7
// Changes vs R6:
//  - k_count -> k_countprep: atomic also records per-edge rank tmp[e] (coalesced);
//    packW folded in. Placement (k_placegemm) then needs NO atomic: pos =
//    rowptr[seg] + tmp[e]; gemm1 fused into the same dispatch (block-split) and
//    reads x as f32 directly (k_f2b + xb round-trip eliminated).
//  - bn+relu fused into gemm2's A-load (k_bnrelu + hb eliminated).
//  - gather2 stats/write iterate output-row-major (s = r*N + n): contiguous
//    1KB writes per wave instead of 4 lines 12.8MB apart.

#define GATHER_GRID 2048
#define SCAN_CHUNK 4096
#define RED_BLOCKS 64
#define PREP_BLOCKS 16
#define COUNT_BLOCKS 2048
#define PLACE_BLOCKS 1024

typedef short bf16x8 __attribute__((ext_vector_type(8)));
typedef float f32x4 __attribute__((ext_vector_type(4)));

static __device__ __forceinline__ float bf2f(unsigned short u) {
  return __uint_as_float(((unsigned)u) << 16);
}
static __device__ __forceinline__ unsigned short f2bf(float f) {
  unsigned u = __float_as_uint(f);
  u += 0x7FFFu + ((u >> 16) & 1u);  // round to nearest even
  return (unsigned short)(u >> 16);
}

__global__ void k_zero(int* __restrict__ cnt, int n) {
  int i = blockIdx.x * blockDim.x + threadIdx.x;
  int stride = gridDim.x * blockDim.x;
  for (int k = i; k < n; k += stride) cnt[k] = 0;
}

// blocks [0,PREP_BLOCKS): pack weights to bf16.  blocks [PREP_BLOCKS,...):
// count edges per segment, record per-edge rank tmp[e] (coalesced write).
__global__ void k_countprep(const int* __restrict__ node_out, const int* __restrict__ rel,
                            int* __restrict__ cnt, int* __restrict__ tmp, int E, int R,
                            const float* __restrict__ Wlin1, const float* __restrict__ Wself1,
                            const float* __restrict__ Wlin2, const float* __restrict__ Wself2,
                            unsigned short* __restrict__ wb1, unsigned short* __restrict__ wb2) {
  if (blockIdx.x < PREP_BLOCKS) {
    int i = blockIdx.x * 256 + threadIdx.x;
    int stride = PREP_BLOCKS * 256;
    int n1 = (R + 1) * 64 * 64;
    int n2 = 2 * 64 * 64;
    for (int k = i; k < n1 + n2; k += stride) {
      if (k < n1) {
        int r = k >> 6, d = k & 63;
        float v;
        if (r < R * 64) {
          int s = r >> 6, j = r & 63;
          v = Wlin1[j * (R * 64) + s * 64 + d];
        } else {
          v = Wself1[(r - R * 64) * 64 + d];
        }
        wb1[k] = f2bf(v);
      } else {
        int k2 = k - n1;
        int r = k2 >> 6, d = k2 & 63;
        float v = (r < 64) ? Wlin2[r * 64 + d] : Wself2[(r - 64) * 64 + d];
        wb2[k2] = f2bf(v);
      }
    }
  } else {
    int i = (blockIdx.x - PREP_BLOCKS) * 256 + threadIdx.x;
    int stride = COUNT_BLOCKS * 256;
    for (int e = i; e < E; e += stride) {
      int seg = node_out[e] * R + rel[e];
      tmp[e] = atomicAdd(&cnt[seg], 1);
    }
  }
}

__global__ __launch_bounds__(256) void k_scan1(const int* __restrict__ cnt,
                                               int* __restrict__ bsum, int NR) {
  __shared__ int red[256];
  int tid = threadIdx.x;
  int base = blockIdx.x * SCAN_CHUNK;
  int s = 0;
  for (int i = tid; i < SCAN_CHUNK; i += 256) {
    int idx = base + i;
    if (idx < NR) s += cnt[idx];
  }
  red[tid] = s;
  __syncthreads();
  for (int off = 128; off > 0; off >>= 1) {
    if (tid < off) red[tid] += red[tid + off];
    __syncthreads();
  }
  if (tid == 0) bsum[blockIdx.x] = red[0];
}

__global__ void k_scan2(const int* __restrict__ bsum, int* __restrict__ bpre,
                        int* __restrict__ rowptr_end, int NB) {
  int lane = threadIdx.x;
  int carry = 0;
  for (int base = 0; base < NB; base += 64) {
    int i = base + lane;
    int v = (i < NB) ? bsum[i] : 0;
    int incl = v;
    #pragma unroll
    for (int off = 1; off < 64; off <<= 1) {
      int u = __shfl_up(incl, off);
      if (lane >= off) incl += u;
    }
    if (i < NB) bpre[i] = carry + incl - v;
    carry += __shfl(incl, 63);
  }
  if (lane == 0) *rowptr_end = carry;
}

__global__ __launch_bounds__(256) void k_scan3(const int* __restrict__ cnt,
                                               const int* __restrict__ bpre,
                                               int* __restrict__ rowptr, int NR) {
  __shared__ int wtot[4];
  int tid = threadIdx.x, lane = tid & 63, wid = tid >> 6;
  int base = blockIdx.x * SCAN_CHUNK + tid * 16;
  int v[16];
  int t = 0;
  #pragma unroll
  for (int i = 0; i < 16; i++) {
    int idx = base + i;
    v[i] = (idx < NR) ? cnt[idx] : 0;
    t += v[i];
  }
  int incl = t;
  #pragma unroll
  for (int off = 1; off < 64; off <<= 1) {
    int u = __shfl_up(incl, off);
    if (lane >= off) incl += u;
  }
  if (lane == 63) wtot[wid] = incl;
  __syncthreads();
  int woff = 0;
  for (int w = 0; w < wid; w++) woff += wtot[w];
  int start = bpre[blockIdx.x] + woff + incl - t;
  #pragma unroll
  for (int i = 0; i < 16; i++) {
    int idx = base + i;
    if (idx < NR) rowptr[idx] = start;
    start += v[i];
  }
}

// blocks [0,mblocks): gemm1 (A = x f32, converted in-register).
// blocks [mblocks,...): place edges (no atomics): ep[rowptr[seg]+tmp[e]].
__global__ __launch_bounds__(256) void k_placegemm(
    // place args
    const float* __restrict__ w, const int* __restrict__ node_out,
    const int* __restrict__ node_in, const int* __restrict__ rel,
    const int* __restrict__ rowptr, const int* __restrict__ tmp,
    int2* __restrict__ ep, int E, int R,
    // gemm args
    const float* __restrict__ xf, int M, const unsigned short* __restrict__ Wb,
    int nslab, unsigned short* __restrict__ outLinB, unsigned short* __restrict__ outSelf,
    int mblocks) {
  if ((int)blockIdx.x < mblocks) {
    int m0 = blockIdx.x * 64;
    int wid = threadIdx.x >> 6;
    int lane = threadIdx.x & 63;
    int mrow = m0 + wid * 16 + (lane & 15);
    int mload = (mrow < M) ? mrow : (M - 1);
    const float* arow = xf + (size_t)mload * 64 + 8 * (lane >> 4);
    float4 af0 = *(const float4*)(arow);
    float4 af1 = *(const float4*)(arow + 4);
    float4 af2 = *(const float4*)(arow + 32);
    float4 af3 = *(const float4*)(arow + 36);
    bf16x8 a0, a1;
    a0[0] = (short)f2bf(af0.x); a0[1] = (short)f2bf(af0.y);
    a0[2] = (short)f2bf(af0.z); a0[3] = (short)f2bf(af0.w);
    a0[4] = (short)f2bf(af1.x); a0[5] = (short)f2bf(af1.y);
    a0[6] = (short)f2bf(af1.z); a0[7] = (short)f2bf(af1.w);
    a1[0] = (short)f2bf(af2.x); a1[1] = (short)f2bf(af2.y);
    a1[2] = (short)f2bf(af2.z); a1[3] = (short)f2bf(af2.w);
    a1[4] = (short)f2bf(af3.x); a1[5] = (short)f2bf(af3.y);
    a1[6] = (short)f2bf(af3.z); a1[7] = (short)f2bf(af3.w);
    int rbase = m0 + wid * 16 + ((lane >> 4) << 2);
    int cbase = lane & 15;
    for (int slab = 0; slab <= nslab; ++slab) {
      const unsigned short* wrow = Wb + ((size_t)slab * 64 + (lane & 15)) * 64 + 8 * (lane >> 4);
      unsigned short* op = (slab < nslab) ? (outLinB + (size_t)slab * M * 64) : outSelf;
      #pragma unroll
      for (int nt = 0; nt < 4; ++nt) {
        bf16x8 b0 = *(const bf16x8*)(wrow + nt * 16 * 64);
        bf16x8 b1 = *(const bf16x8*)(wrow + nt * 16 * 64 + 32);
        f32x4 c = {};
        c = __builtin_amdgcn_mfma_f32_16x16x32_bf16(a0, b0, c, 0, 0, 0);
        c = __builtin_amdgcn_mfma_f32_16x16x32_bf16(a1, b1, c, 0, 0, 0);
        int col = nt * 16 + cbase;
        #pragma unroll
        for (int rg = 0; rg < 4; ++rg) {
          int grow = rbase + rg;
          if (grow < M) op[(size_t)grow * 64 + col] = f2bf(c[rg]);
        }
      }
    }
  } else {
    int i = ((int)blockIdx.x - mblocks) * 256 + threadIdx.x;
    int stride = PLACE_BLOCKS * 256;
    for (int e = i; e < E; e += stride) {
      int rr = rel[e];
      int seg = node_out[e] * R + rr;
      int pos = rowptr[seg] + tmp[e];
      ep[pos] = make_int2(node_in[e] | (rr << 16), __float_as_int(w[e]));
    }
  }
}

// per-segment weight normalization in-place: ep.w /= sum(seg w)
__global__ void k_norm(const int* __restrict__ rowptr, int2* __restrict__ ep, int NR) {
  int s = blockIdx.x * blockDim.x + threadIdx.x;
  if (s >= NR) return;
  int k0 = rowptr[s], k1 = rowptr[s + 1];
  if (k0 >= k1) return;
  float d = 0.f;
  for (int k = k0; k < k1; k++) d += __int_as_float(ep[k].y);
  float inv = 1.f / d;
  for (int k = k0; k < k1; k++) {
    int2 v = ep[k];
    v.y = __float_as_int(__int_as_float(v.y) * inv);
    ep[k] = v;
  }
}

// gemm2 with fused bn+relu on A (h_pre, bf16) using ss1.
__global__ __launch_bounds__(256) void k_gemm2bn(
    const unsigned short* __restrict__ hp, int M,
    const unsigned short* __restrict__ Wb, int nslab,
    const float* __restrict__ ss,
    unsigned short* __restrict__ outLinB, unsigned short* __restrict__ outSelf) {
  __shared__ float sss[128];
  if (threadIdx.x < 128) sss[threadIdx.x] = ss[threadIdx.x];
  __syncthreads();
  int m0 = blockIdx.x * 64;
  int wid = threadIdx.x >> 6;
  int lane = threadIdx.x & 63;
  int mrow = m0 + wid * 16 + (lane & 15);
  int mload = (mrow < M) ? mrow : (M - 1);
  int cb = 8 * (lane >> 4);
  const unsigned short* arow = hp + (size_t)mload * 64 + cb;
  ushort4 u0 = *(const ushort4*)(arow);
  ushort4 u1 = *(const ushort4*)(arow + 4);
  ushort4 u2 = *(const ushort4*)(arow + 32);
  ushort4 u3 = *(const ushort4*)(arow + 36);
  bf16x8 a0, a1;
  #pragma unroll
  for (int j = 0; j < 4; j++) {
    unsigned short uu0 = (&u0.x)[j], uu1 = (&u1.x)[j], uu2 = (&u2.x)[j], uu3 = (&u3.x)[j];
    a0[j]     = (short)f2bf(fmaxf(fmaf(bf2f(uu0), sss[cb + j],      sss[64 + cb + j]), 0.f));
    a0[j + 4] = (short)f2bf(fmaxf(fmaf(bf2f(uu1), sss[cb + 4 + j],  sss[64 + cb + 4 + j]), 0.f));
    a1[j]     = (short)f2bf(fmaxf(fmaf(bf2f(uu2), sss[cb + 32 + j], sss[64 + cb + 32 + j]), 0.f));
    a1[j + 4] = (short)f2bf(fmaxf(fmaf(bf2f(uu3), sss[cb + 36 + j], sss[64 + cb + 36 + j]), 0.f));
  }
  int rbase = m0 + wid * 16 + ((lane >> 4) << 2);
  int cbase = lane & 15;
  for (int slab = 0; slab <= nslab; ++slab) {
    const unsigned short* wrow = Wb + ((size_t)slab * 64 + (lane & 15)) * 64 + 8 * (lane >> 4);
    unsigned short* op = (slab < nslab) ? (outLinB + (size_t)slab * M * 64) : outSelf;
    #pragma unroll
    for (int nt = 0; nt < 4; ++nt) {
      bf16x8 b0 = *(const bf16x8*)(wrow + nt * 16 * 64);
      bf16x8 b1 = *(const bf16x8*)(wrow + nt * 16 * 64 + 32);
      f32x4 c = {};
      c = __builtin_amdgcn_mfma_f32_16x16x32_bf16(a0, b0, c, 0, 0, 0);
      c = __builtin_amdgcn_mfma_f32_16x16x32_bf16(a1, b1, c, 0, 0, 0);
      int col = nt * 16 + cbase;
      #pragma unroll
      for (int rg = 0; rg < 4; ++rg) {
        int grow = rbase + rg;
        if (grow < M) op[(size_t)grow * 64 + col] = f2bf(c[rg]);
      }
    }
  }
}

// layer1 gather, shuffle-free: 16-lane group per node, serial over its edges
__global__ __launch_bounds__(256) void k_gather1(
    const int* __restrict__ rowptr, const int2* __restrict__ ep,
    const unsigned short* __restrict__ y1, const unsigned short* __restrict__ s1,
    unsigned short* __restrict__ h_pre, float* __restrict__ part, int N, int R) {
  int lane = threadIdx.x & 63;
  int wid = threadIdx.x >> 6;
  int l16 = lane & 15;
  int lg = lane >> 4;
  int c0 = l16 * 4;
  int grp = blockIdx.x * 16 + wid * 4 + lg;
  int ngrp = gridDim.x * 16;
  float lsum[4] = {0.f, 0.f, 0.f, 0.f}, lsq[4] = {0.f, 0.f, 0.f, 0.f};
  for (int n = grp; n < N; n += ngrp) {
    int k = rowptr[n * R];
    int k1 = rowptr[n * R + R];
    float a0 = 0.f, a1 = 0.f, a2 = 0.f, a3 = 0.f;
    for (; k + 1 < k1; k += 2) {
      int2 pA = ep[k];
      int2 pB = ep[k + 1];
      ushort4 uA = *(const ushort4*)&y1[((size_t)((pA.x >> 16) * N + (pA.x & 0xFFFF))) * 64 + c0];
      ushort4 uB = *(const ushort4*)&y1[((size_t)((pB.x >> 16) * N + (pB.x & 0xFFFF))) * 64 + c0];
      float wA = __int_as_float(pA.y), wB = __int_as_float(pB.y);
      a0 = fmaf(wA, bf2f(uA.x), a0); a1 = fmaf(wA, bf2f(uA.y), a1);
      a2 = fmaf(wA, bf2f(uA.z), a2); a3 = fmaf(wA, bf2f(uA.w), a3);
      a0 = fmaf(wB, bf2f(uB.x), a0); a1 = fmaf(wB, bf2f(uB.y), a1);
      a2 = fmaf(wB, bf2f(uB.z), a2); a3 = fmaf(wB, bf2f(uB.w), a3);
    }
    if (k < k1) {
      int2 p = ep[k];
      float w = __int_as_float(p.y);
      ushort4 u = *(const ushort4*)&y1[((size_t)((p.x >> 16) * N + (p.x & 0xFFFF))) * 64 + c0];
      a0 = fmaf(w, bf2f(u.x), a0); a1 = fmaf(w, bf2f(u.y), a1);
      a2 = fmaf(w, bf2f(u.z), a2); a3 = fmaf(w, bf2f(u.w), a3);
    }
    ushort4 su = *(const ushort4*)&s1[(size_t)n * 64 + c0];
    float v0 = a0 + bf2f(su.x), v1 = a1 + bf2f(su.y);
    float v2 = a2 + bf2f(su.z), v3 = a3 + bf2f(su.w);
    ushort4 o; o.x = f2bf(v0); o.y = f2bf(v1); o.z = f2bf(v2); o.w = f2bf(v3);
    *(ushort4*)&h_pre[(size_t)n * 64 + c0] = o;
    lsum[0] += v0; lsq[0] += v0 * v0;
    lsum[1] += v1; lsq[1] += v1 * v1;
    lsum[2] += v2; lsq[2] += v2 * v2;
    lsum[3] += v3; lsq[3] += v3 * v3;
  }
  __shared__ float sp[16][64], sq[16][64];
  int g = wid * 4 + lg;
  #pragma unroll
  for (int i = 0; i < 4; i++) { sp[g][c0 + i] = lsum[i]; sq[g][c0 + i] = lsq[i]; }
  __syncthreads();
  if (threadIdx.x < 64) {
    int j = threadIdx.x;
    float s = 0.f, q = 0.f;
    #pragma unroll
    for (int gg = 0; gg < 16; gg++) { s += sp[gg][j]; q += sq[gg][j]; }
    part[(size_t)blockIdx.x * 128 + j] = s;
    part[(size_t)blockIdx.x * 128 + 64 + j] = q;
  }
}

// layer2 pass A (stats): output-row-major segment order (s = r*N + n).
__global__ __launch_bounds__(256) void k_gather2_stats(
    const int* __restrict__ rowptr, const int2* __restrict__ ep,
    const unsigned short* __restrict__ z, const unsigned short* __restrict__ s2,
    float* __restrict__ part, int N, int R) {
  int lane = threadIdx.x & 63;
  int wid = threadIdx.x >> 6;
  int l16 = lane & 15;
  int lg = lane >> 4;
  int c0 = l16 * 4;
  int grp = blockIdx.x * 16 + wid * 4 + lg;
  int ngrp = gridDim.x * 16;
  int NR = N * R;
  float lsum[4] = {0.f, 0.f, 0.f, 0.f}, lsq[4] = {0.f, 0.f, 0.f, 0.f};
  for (int s = grp; s < NR; s += ngrp) {
    unsigned r = (unsigned)s / (unsigned)N;
    int n = s - (int)r * N;
    int seg = n * R + (int)r;
    int k = rowptr[seg];
    int k1 = rowptr[seg + 1];
    float a0 = 0.f, a1 = 0.f, a2 = 0.f, a3 = 0.f;
    for (; k + 1 < k1; k += 2) {
      int2 pA = ep[k];
      int2 pB = ep[k + 1];
      ushort4 uA = *(const ushort4*)&z[(size_t)(pA.x & 0xFFFF) * 64 + c0];
      ushort4 uB = *(const ushort4*)&z[(size_t)(pB.x & 0xFFFF) * 64 + c0];
      float wA = __int_as_float(pA.y), wB = __int_as_float(pB.y);
      a0 = fmaf(wA, bf2f(uA.x), a0); a1 = fmaf(wA, bf2f(uA.y), a1);
      a2 = fmaf(wA, bf2f(uA.z), a2); a3 = fmaf(wA, bf2f(uA.w), a3);
      a0 = fmaf(wB, bf2f(uB.x), a0); a1 = fmaf(wB, bf2f(uB.y), a1);
      a2 = fmaf(wB, bf2f(uB.z), a2); a3 = fmaf(wB, bf2f(uB.w), a3);
    }
    if (k < k1) {
      int2 p = ep[k];
      float w = __int_as_float(p.y);
      ushort4 u = *(const ushort4*)&z[(size_t)(p.x & 0xFFFF) * 64 + c0];
      a0 = fmaf(w, bf2f(u.x), a0); a1 = fmaf(w, bf2f(u.y), a1);
      a2 = fmaf(w, bf2f(u.z), a2); a3 = fmaf(w, bf2f(u.w), a3);
    }
    ushort4 su = *(const ushort4*)&s2[(size_t)n * 64 + c0];
    float v0 = a0 + bf2f(su.x), v1 = a1 + bf2f(su.y);
    float v2 = a2 + bf2f(su.z), v3 = a3 + bf2f(su.w);
    lsum[0] += v0; lsq[0] += v0 * v0;
    lsum[1] += v1; lsq[1] += v1 * v1;
    lsum[2] += v2; lsq[2] += v2 * v2;
    lsum[3] += v3; lsq[3] += v3 * v3;
  }
  __shared__ float sp[16][64], sq[16][64];
  int g = wid * 4 + lg;
  #pragma unroll
  for (int i = 0; i < 4; i++) { sp[g][c0 + i] = lsum[i]; sq[g][c0 + i] = lsq[i]; }
  __syncthreads();
  if (threadIdx.x < 64) {
    int j = threadIdx.x;
    float s = 0.f, q = 0.f;
    #pragma unroll
    for (int gg = 0; gg < 16; gg++) { s += sp[gg][j]; q += sq[gg][j]; }
    part[(size_t)blockIdx.x * 128 + j] = s;
    part[(size_t)blockIdx.x * 128 + 64 + j] = q;
  }
}

// layer2 pass B (write): output-row-major; contiguous writes to d_out.
__global__ __launch_bounds__(256) void k_gather2_write(
    const int* __restrict__ rowptr, const int2* __restrict__ ep,
    const unsigned short* __restrict__ z, const unsigned short* __restrict__ s2,
    const float* __restrict__ ss, float* __restrict__ out, int N, int R) {
  int lane = threadIdx.x & 63;
  int wid = threadIdx.x >> 6;
  int l16 = lane & 15;
  int lg = lane >> 4;
  int c0 = l16 * 4;
  float sc0 = ss[c0], sc1 = ss[c0 + 1], sc2 = ss[c0 + 2], sc3 = ss[c0 + 3];
  float sh0 = ss[64 + c0], sh1 = ss[64 + c0 + 1], sh2 = ss[64 + c0 + 2], sh3 = ss[64 + c0 + 3];
  int grp = blockIdx.x * 16 + wid * 4 + lg;
  int ngrp = gridDim.x * 16;
  int NR = N * R;
  for (int s = grp; s < NR; s += ngrp) {
    unsigned r = (unsigned)s / (unsigned)N;
    int n = s - (int)r * N;
    int seg = n * R + (int)r;
    int k = rowptr[seg];
    int k1 = rowptr[seg + 1];
    float a0 = 0.f, a1 = 0.f, a2 = 0.f, a3 = 0.f;
    for (; k + 1 < k1; k += 2) {
      int2 pA = ep[k];
      int2 pB = ep[k + 1];
      ushort4 uA = *(const ushort4*)&z[(size_t)(pA.x & 0xFFFF) * 64 + c0];
      ushort4 uB = *(const ushort4*)&z[(size_t)(pB.x & 0xFFFF) * 64 + c0];
      float wA = __int_as_float(pA.y), wB = __int_as_float(pB.y);
      a0 = fmaf(wA, bf2f(uA.x), a0); a1 = fmaf(wA, bf2f(uA.y), a1);
      a2 = fmaf(wA, bf2f(uA.z), a2); a3 = fmaf(wA, bf2f(uA.w), a3);
      a0 = fmaf(wB, bf2f(uB.x), a0); a1 = fmaf(wB, bf2f(uB.y), a1);
      a2 = fmaf(wB, bf2f(uB.z), a2); a3 = fmaf(wB, bf2f(uB.w), a3);
    }
    if (k < k1) {
      int2 p = ep[k];
      float w = __int_as_float(p.y);
      ushort4 u = *(const ushort4*)&z[(size_t)(p.x & 0xFFFF) * 64 + c0];
      a0 = fmaf(w, bf2f(u.x), a0); a1 = fmaf(w, bf2f(u.y), a1);
      a2 = fmaf(w, bf2f(u.z), a2); a3 = fmaf(w, bf2f(u.w), a3);
    }
    ushort4 su = *(const ushort4*)&s2[(size_t)n * 64 + c0];
    float v0 = fmaxf(fmaf(a0 + bf2f(su.x), sc0, sh0), 0.f);
    float v1 = fmaxf(fmaf(a1 + bf2f(su.y), sc1, sh1), 0.f);
    float v2 = fmaxf(fmaf(a2 + bf2f(su.z), sc2, sh2), 0.f);
    float v3 = fmaxf(fmaf(a3 + bf2f(su.w), sc3, sh3), 0.f);
    *(float4*)&out[(size_t)s * 64 + c0] = make_float4(v0, v1, v2, v3);
  }
}

// stage 1: reduce part[GATHER_GRID][128] -> part2[RED_BLOCKS][128]
__global__ __launch_bounds__(256) void k_red1(const float* __restrict__ part,
                                              float* __restrict__ part2, int P) {
  int j = threadIdx.x & 127;
  int g = threadIdx.x >> 7;
  int rows = P / RED_BLOCKS;
  int base = blockIdx.x * rows;
  float acc = 0.f;
  for (int i = g; i < rows; i += 2) acc += part[(size_t)(base + i) * 128 + j];
  __shared__ float red[2][128];
  red[g][j] = acc;
  __syncthreads();
  if (threadIdx.x < 128) part2[(size_t)blockIdx.x * 128 + j] = red[0][j] + red[1][j];
}

__global__ __launch_bounds__(1024) void k_bnstats(
    const float* __restrict__ part, int P, float M,
    const float* __restrict__ gamma, const float* __restrict__ beta,
    float* __restrict__ ss) {
  __shared__ float red[1024];
  int tid = threadIdx.x;
  int j = tid & 127;
  int g = tid >> 7;
  float acc = 0.f;
  for (int i = g; i < P; i += 8) acc += part[(size_t)i * 128 + j];
  red[tid] = acc;
  __syncthreads();
  if (tid < 128) {
    float s = 0.f;
    for (int gg = 0; gg < 8; gg++) s += red[gg * 128 + tid];
    red[tid] = s;
  }
  __syncthreads();
  if (tid < 64) {
    float s = red[tid], q = red[64 + tid];
    float mean = s / M;
    float var = q / M - mean * mean;
    float sc = gamma[tid] / sqrtf(var + 1e-5f);
    ss[tid] = sc;
    ss[64 + tid] = beta[tid] - mean * sc;
  }
}

extern "C" void kernel_launch(void* const* d_in, const int* in_sizes, int n_in,
                              void* d_out, int out_size, void* d_ws, size_t ws_size,
                              hipStream_t stream) {
  const float* x        = (const float*)d_in[0];
  const float* edge_w   = (const float*)d_in[1];
  const float* W_lin1   = (const float*)d_in[2];
  const float* W_self1  = (const float*)d_in[4];
  const float* gamma1   = (const float*)d_in[6];
  const float* beta1    = (const float*)d_in[7];
  const float* W_lin2   = (const float*)d_in[8];
  const float* W_self2  = (const float*)d_in[10];
  const float* gamma2   = (const float*)d_in[12];
  const float* beta2    = (const float*)d_in[13];
  const int* node_in    = (const int*)d_in[14];
  const int* node_out   = (const int*)d_in[15];
  const int* relation   = (const int*)d_in[16];

  int N = in_sizes[0] / 64;           // 50000
  int E = in_sizes[1];                // 800000
  int R = in_sizes[2] / (64 * 64);    // 8
  int NR = N * R;
  int NB = (NR + SCAN_CHUNK - 1) / SCAN_CHUNK;

  char* p = (char*)d_ws;
  auto alloc = [&](size_t bytes) { char* r = p; p += (bytes + 255) & ~(size_t)255; return r; };
  int* cnt      = (int*)alloc(4ull * NR);
  int* rowptr   = (int*)alloc(4ull * (NR + 1));
  int* tmp      = (int*)alloc(4ull * E);
  int* bsum     = (int*)alloc(4ull * NB);
  int* bpre     = (int*)alloc(4ull * NB);
  int2* ep      = (int2*)alloc(8ull * E);
  unsigned short* wb1 = (unsigned short*)alloc(2ull * (R + 1) * 64 * 64);
  unsigned short* wb2 = (unsigned short*)alloc(2ull * 2 * 64 * 64);
  unsigned short* s1    = (unsigned short*)alloc(2ull * N * 64);
  unsigned short* h_pre = (unsigned short*)alloc(2ull * N * 64);
  unsigned short* z     = (unsigned short*)alloc(2ull * N * 64);
  unsigned short* s2    = (unsigned short*)alloc(2ull * N * 64);
  float* part   = (float*)alloc(4ull * GATHER_GRID * 128);
  float* part2  = (float*)alloc(4ull * RED_BLOCKS * 128);
  float* ss1    = (float*)alloc(4ull * 128);
  float* ss2    = (float*)alloc(4ull * 128);

  // d_out scratch: y1 bf16 [0, 51.2MB) — dead before gather2_write rewrites d_out.
  unsigned short* y1 = (unsigned short*)d_out;

  int mblocks = (N + 63) / 64;

  k_zero<<<256, 256, 0, stream>>>(cnt, NR);
  k_countprep<<<PREP_BLOCKS + COUNT_BLOCKS, 256, 0, stream>>>(
      node_out, relation, cnt, tmp, E, R, W_lin1, W_self1, W_lin2, W_self2, wb1, wb2);
  k_scan1<<<NB, 256, 0, stream>>>(cnt, bsum, NR);
  k_scan2<<<1, 64, 0, stream>>>(bsum, bpre, &rowptr[NR], NB);
  k_scan3<<<NB, 256, 0, stream>>>(cnt, bpre, rowptr, NR);
  k_placegemm<<<mblocks + PLACE_BLOCKS, 256, 0, stream>>>(
      edge_w, node_out, node_in, relation, rowptr, tmp, ep, E, R,
      x, N, wb1, R, y1, s1, mblocks);
  k_norm<<<(NR + 255) / 256, 256, 0, stream>>>(rowptr, ep, NR);

  // layer 1 gather + stats
  k_gather1<<<GATHER_GRID, 256, 0, stream>>>(rowptr, ep, y1, s1, h_pre, part, N, R);
  k_red1<<<RED_BLOCKS, 256, 0, stream>>>(part, part2, GATHER_GRID);
  k_bnstats<<<1, 1024, 0, stream>>>(part2, RED_BLOCKS, (float)N, gamma1, beta1, ss1);

  // layer 2: gemm (bn+relu fused on A) -> stats -> write
  k_gemm2bn<<<mblocks, 256, 0, stream>>>(h_pre, N, wb2, 1, ss1, z, s2);
  k_gather2_stats<<<GATHER_GRID, 256, 0, stream>>>(rowptr, ep, z, s2, part, N, R);
  k_red1<<<RED_BLOCKS, 256, 0, stream>>>(part, part2, GATHER_GRID);
  k_bnstats<<<1, 1024, 0, stream>>>(part2, RED_BLOCKS, (float)N * R, gamma2, beta2, ss2);
  k_gather2_write<<<GATHER_GRID, 256, 0, stream>>>(rowptr, ep, z, s2, ss2, (float*)d_out, N, R);
}